// Round 15
// baseline (277.694 us; speedup 1.0000x reference)
//
#include <hip/hip_runtime.h>
#include <hip/hip_bf16.h>

// ChunkedCrossAttention (RETRO-style), MI355X gfx950.
// N=2048 M=64 K=2 R=512 D=1024 H=16 DH=64 LCH=32
//
// Round 15: gemm256h keeps r14's 2-blocks/CU shape (256thr, BM256/BN128/BK32,
// 48KB LDS) but replaces the broken 64B-row swizzle (13.4M bank conflicts)
// with the PROVEN 128B-row scheme: two 64B tile-rows packed per 128B LDS row,
// 16B-slot XOR by (ldsrow&7) on both stage-source and read (rule #21).

using u16 = unsigned short;
using u32 = unsigned int;

typedef float  f32x4   __attribute__((ext_vector_type(4)));
typedef __bf16 bf16x8v __attribute__((ext_vector_type(8)));
typedef __bf16 bf16x4v __attribute__((ext_vector_type(4)));
typedef short  s16x4   __attribute__((ext_vector_type(4)));
typedef u16    u16x8   __attribute__((ext_vector_type(8)));
typedef u16    u16x4v  __attribute__((ext_vector_type(4)));

#define SCALE_LOG2E (1.4426950408889634f / 32.0f)

__device__ __forceinline__ u16 f2b(float f){ return __builtin_bit_cast(u16, (__bf16)f); }
// XOR swizzle on 16B slots within 128B LDS rows (gemm128)
__device__ __forceinline__ int swz(int row, int cb){ return row*128 + (cb ^ ((row & 7) << 4)); }

// async global->LDS, 16B per lane, wave-uniform LDS base (guide §5 / m97)
__device__ __forceinline__ void gl_lds16(const void* g, void* l) {
    __builtin_amdgcn_global_load_lds(
        (const __attribute__((address_space(1))) unsigned int*)(unsigned long long)g,
        (__attribute__((address_space(3))) unsigned int*)(unsigned int)(unsigned long long)l,
        16, 0, 0);
}

// ===========================================================================
// gemm256h: 256x128 tile, BK=32 dbuf, 48KB LDS, 2 blocks/CU.
// C(MxN) = A(MxKc) @ B(NxKc)^T, bf16. REQUIRES M%256==0, N%128==0, Kc%32==0.
// 256 threads = 4 waves (wr over M-halves, wc over N-halves); per-wave
// output 128x64 (acc 128 f32; ~232 combined regs, fits 2 waves/SIMD).
// LDS: A[2][16KB] at 0, B[2][8KB] at 32K. Two 64B tile-rows per 128B LDS
// row; 16B slots XOR-swizzled by (ldsrow&7) (proven r10 family):
//   stage: thread t, issue j -> ldsrow r=j*32+(t>>3), phys slot t&7,
//     logical sl=(t&7)^((t>>3)&7); src tile-row 64j+2(t>>3)+(sl>>2),
//     elem off (sl&3)*8.  (one base ptr + j*64*ld per issue)
//   read: tile row x -> byte (x>>1)*128 + (((x&1)*4+lg)^((x>>1)&7))*16;
//     x=base+16i -> +1024i, lane constants invariant. 2-way banks = free.
// Per tile: 12 ds_read_b128 | stage(t+1) 6 gl_lds | 32 MFMA | vmcnt(0) |
// 1 barrier. Residual stalls overlap with the co-resident block (m114).
// OM=3: bn<1024 -> Ka row-major; bn>=1024 -> Vt^T via 2-pass 32KB LDS
// transpose, coalesced 16B stores.
// ===========================================================================
template<int OM>
__global__ __launch_bounds__(256, 2)
void gemm256h(const u16* __restrict__ Ap, int lda,
              const u16* __restrict__ Bp, int ldb,
              void* __restrict__ Cp, void* __restrict__ Cp2,
              int M, int Kc, int nNt)
{
    __shared__ char Ls[49152];
    char* const Abase = Ls;            // [2][16KB]
    char* const Bbase = Ls + 32768;    // [2][8KB]

    const int tid  = threadIdx.x;
    const int lane = tid & 63, wave = tid >> 6;   // 4 waves
    const int li = lane & 15, lg = lane >> 4;
    const int wr = wave >> 1, wc = wave & 1;

    const int nwg  = gridDim.x;
    const int lin  = blockIdx.x;
    const int lin2 = (lin & 7) * (nwg >> 3) + (lin >> 3);   // XCD chunk swizzle
    const long bm = (long)(lin2 / nNt) * 256;
    const long bn = (long)(lin2 % nNt) * 128;

    // --- stage-side inverse swizzle (per thread, hoisted) ---
    const int sl    = (tid & 7) ^ ((tid >> 3) & 7);          // logical slot
    const int xbase = 2*(tid >> 3) + (sl >> 2);              // src tile row, issue 0
    const int selc  = (sl & 3) * 8;                          // src elem offset
    const u16* const pAsrc = Ap + (bm + xbase)*(long)lda + selc;
    const u16* const pBsrc = Bp + (bn + xbase)*(long)ldb + selc;
    const long l64a = 64*(long)lda, l64b = 64*(long)ldb;

    auto stA = [&](int t) {                        // 16KB = 4 x 4KB issues
        char* d = Abase + (t & 1)*16384 + wave*1024;
        const u16* p = pAsrc + (long)t*32;
        gl_lds16(p,          d);
        gl_lds16(p +   l64a, d + 4096);
        gl_lds16(p + 2*l64a, d + 8192);
        gl_lds16(p + 3*l64a, d + 12288);
    };
    auto stB = [&](int t) {                        // 8KB = 2 x 4KB issues
        char* d = Bbase + (t & 1)*8192 + wave*1024;
        const u16* p = pBsrc + (long)t*32;
        gl_lds16(p,        d);
        gl_lds16(p + l64b, d + 4096);
    };

    const int NT = Kc >> 5;   // 32

    stA(0); stB(0);
    asm volatile("s_waitcnt vmcnt(0)" ::: "memory");
    asm volatile("s_barrier" ::: "memory");

    // --- read-side lane constants ---
    const int axb  = wr*128 + li;                  // A tile row base (+16i)
    const int aoff = (axb >> 1)*128 + ((((axb & 1)*4 + lg) ^ ((axb >> 1) & 7)) << 4);
    const int bxb  = wc*64 + li;                   // B tile row base (+16nt)
    const int boff = (bxb >> 1)*128 + ((((bxb & 1)*4 + lg) ^ ((bxb >> 1) & 7)) << 4);

    f32x4 acc[8][4] = {};
    bf16x8v a[8], b[4];

    for (int t = 0; t < NT; ++t) {
        char* At = Abase + (t & 1)*16384;
        char* Bt = Bbase + (t & 1)*8192;

        #pragma unroll
        for (int i = 0; i < 4; i++) b[i] = *(const bf16x8v*)(Bt + boff + i*1024);
        #pragma unroll
        for (int i = 0; i < 8; i++) a[i] = *(const bf16x8v*)(At + aoff + i*1024);
        if (t + 1 < NT) { stA(t + 1); stB(t + 1); }
        __builtin_amdgcn_sched_barrier(0);
        __builtin_amdgcn_s_setprio(1);
        #pragma unroll
        for (int ai = 0; ai < 8; ai++)
            #pragma unroll
            for (int nt = 0; nt < 4; nt++)
                acc[ai][nt] = __builtin_amdgcn_mfma_f32_16x16x32_bf16(
                    a[ai], b[nt], acc[ai][nt], 0, 0, 0);
        __builtin_amdgcn_s_setprio(0);
        if (t + 1 < NT) { asm volatile("s_waitcnt vmcnt(0)" ::: "memory"); }
        asm volatile("s_barrier" ::: "memory");   // publish t+1; WAR guard
    }

    if (OM == 3 && bn >= 1024) {
        // --- V-block epilogue: 2-pass LDS transpose (32KB) -> coalesced ---
        u16* Vt = (u16*)Cp2;
        #pragma unroll
        for (int nh = 0; nh < 2; nh++) {
            if (wc == nh) {
                #pragma unroll
                for (int ai = 0; ai < 8; ai++) {
                    const int m0 = wr*128 + ai*16 + lg*4;     // 4-aligned
                    #pragma unroll
                    for (int nt = 0; nt < 4; nt++) {
                        const int rr = nt*16 + li;            // 0..63 local n
                        f32x4 c = acc[ai][nt];
                        bf16x4v w;
                        #pragma unroll
                        for (int j = 0; j < 4; j++) w[j] = (__bf16)c[j];
                        *(bf16x4v*)(Ls + rr*512 + ((m0*2) ^ ((rr & 31) << 4))) = w;
                    }
                }
            }
            __syncthreads();
            const int rr  = tid >> 2;          // 0..63
            const int seg = tid & 3;           // 64 m-elems each
            u16* dst = Vt + (bn - 1024 + nh*64 + rr)*32768L + bm + seg*64;
            #pragma unroll
            for (int i = 0; i < 8; i++) {
                const int mb = (seg*64 + i*8) * 2;
                uint4 v = *(const uint4*)(Ls + rr*512 + (mb ^ ((rr & 31) << 4)));
                *(uint4*)(dst + i*8) = v;
            }
            __syncthreads();
        }
    } else if (OM == 3) {
        // --- K-block epilogue: row-major 2B stores ---
        u16* Ka = (u16*)Cp;
        #pragma unroll
        for (int ai = 0; ai < 8; ai++) {
            #pragma unroll
            for (int nt = 0; nt < 4; nt++) {
                f32x4 c = acc[ai][nt];
                const long row0 = bm + wr*128 + ai*16 + lg*4;
                const long col  = bn + wc*64 + nt*16 + li;
                #pragma unroll
                for (int j = 0; j < 4; j++)
                    Ka[(row0 + j)*1024 + col] = f2b(c[j]);
            }
        }
    }
}

// ---------------------------------------------------------------------------
// 128x128x64-step GEMM (Q/Wo projections + fallback), unchanged.
// ---------------------------------------------------------------------------
template<bool AF32, int OM>
__global__ __launch_bounds__(256)
void gemm128(const void* __restrict__ Ap, int lda,
             const u16* __restrict__ Bp, int ldb,
             void* __restrict__ Cp, void* __restrict__ Cp2,
             int M, int Kc, int row_off, int nNt)
{
    __shared__ char As[128*128];
    __shared__ char Bs[128*128];
    const int tid  = threadIdx.x;
    const int lane = tid & 63, wave = tid >> 6;
    const int li = lane & 15, lg = lane >> 4;
    const int wr = wave >> 1, wc = wave & 1;

    const int nwg  = gridDim.x;
    const int lin  = blockIdx.x;
    const int lin2 = (lin & 7) * (nwg >> 3) + (lin >> 3);
    const long bm = (long)(lin2 / nNt) * 128;
    const long bn = (long)(lin2 % nNt) * 128;

    const int grow = wave*32 + (lane >> 3);
    const int gcol = ((lane & 7) ^ (lane >> 3)) << 3;
    const int sr = tid >> 1, sc = (tid & 1) * 32;
    long arow_f = bm + sr; if (arow_f >= M) arow_f = M - 1;
    long arow_g[4];
    #pragma unroll
    for (int j = 0; j < 4; j++) {
        long r = bm + grow + j*8;
        arow_g[j] = (r < M) ? r : (M - 1);
    }

    f32x4 acc[4][4] = {};

    for (int k0 = 0; k0 < Kc; k0 += 64) {
        float4 a4[8];
        if (AF32) {
            const float4* ap = (const float4*)((const float*)Ap + arow_f*lda + k0 + sc);
            #pragma unroll
            for (int i = 0; i < 8; i++) a4[i] = ap[i];
        }
        __syncthreads();
        if (!AF32) {
            #pragma unroll
            for (int j = 0; j < 4; j++)
                gl_lds16((const u16*)Ap + arow_g[j]*(long)lda + k0 + gcol,
                         As + (wave*4 + j)*1024);
        }
        #pragma unroll
        for (int j = 0; j < 4; j++)
            gl_lds16(Bp + (bn + grow + j*8)*(long)ldb + k0 + gcol,
                     Bs + (wave*4 + j)*1024);
        if (AF32) {
            #pragma unroll
            for (int i = 0; i < 4; i++) {
                float4 f0 = a4[2*i], f1 = a4[2*i+1];
                bf16x8v w;
                w[0]=(__bf16)f0.x; w[1]=(__bf16)f0.y; w[2]=(__bf16)f0.z; w[3]=(__bf16)f0.w;
                w[4]=(__bf16)f1.x; w[5]=(__bf16)f1.y; w[6]=(__bf16)f1.z; w[7]=(__bf16)f1.w;
                *(bf16x8v*)(As + swz(sr, sc*2 + i*16)) = w;
            }
        }
        __syncthreads();
        #pragma unroll
        for (int es = 0; es < 2; es++) {
            bf16x8v af[4], bfv[4];
            #pragma unroll
            for (int mt = 0; mt < 4; mt++)
                af[mt] = *(const bf16x8v*)(As + swz(wr*64 + mt*16 + li, es*64 + lg*16));
            #pragma unroll
            for (int nt = 0; nt < 4; nt++)
                bfv[nt] = *(const bf16x8v*)(Bs + swz(wc*64 + nt*16 + li, es*64 + lg*16));
            #pragma unroll
            for (int mt = 0; mt < 4; mt++)
                #pragma unroll
                for (int nt = 0; nt < 4; nt++)
                    acc[mt][nt] = __builtin_amdgcn_mfma_f32_16x16x32_bf16(
                        af[mt], bfv[nt], acc[mt][nt], 0, 0, 0);
        }
    }

    #pragma unroll
    for (int mt = 0; mt < 4; mt++) {
        #pragma unroll
        for (int nt = 0; nt < 4; nt++) {
            f32x4 c = acc[mt][nt];
            const long row0 = bm + wr*64 + mt*16 + lg*4;
            const long col  = bn + wc*64 + nt*16 + li;
            if (OM == 0) {
                u16* C = (u16*)Cp;
                #pragma unroll
                for (int j = 0; j < 4; j++) {
                    long rg = row0 + j;
                    if (rg < M) C[rg*1024 + col] = f2b(c[j]);
                }
            } else if (OM == 2) {
                float* C = (float*)Cp;
                #pragma unroll
                for (int j = 0; j < 4; j++) {
                    long rg = row0 + j;
                    if (rg < M) C[(row_off + rg)*1024 + col] = c[j];
                }
            } else {
                if (col < 1024) {
                    u16* Ka = (u16*)Cp;
                    #pragma unroll
                    for (int j = 0; j < 4; j++) Ka[(row0 + j)*1024 + col] = f2b(c[j]);
                } else {
                    u16* Vt = (u16*)Cp2;
                    bf16x4v w;
                    #pragma unroll
                    for (int j = 0; j < 4; j++) w[j] = (__bf16)c[j];
                    *(bf16x4v*)(Vt + (col - 1024)*32768L + row0) = w;
                }
            }
        }
    }
}

// ---------------------------------------------------------------------------
// Fused attention: grid (31, 16), 4 waves stride 64 substeps (r10 best).
// ---------------------------------------------------------------------------
__global__ __launch_bounds__(256)
void attn_kernel(const u16* __restrict__ Qa, const u16* __restrict__ Ka,
                 const u16* __restrict__ Vt, u16* __restrict__ Om)
{
    const int u = blockIdx.x, h = blockIdx.y;
    const int tid = threadIdx.x;
    const int lane = tid & 63, wave = tid >> 6;
    const int li = lane & 15, lg = lane >> 4;

    bf16x8v qf[4][2];
    #pragma unroll
    for (int qt = 0; qt < 4; qt++)
        #pragma unroll
        for (int es = 0; es < 2; es++)
            qf[qt][es] = *(const bf16x8v*)(Qa + (long)(63 + u*64 + qt*16 + li)*1024
                                              + h*64 + es*32 + lg*8);

    f32x4 acc[4][4] = {};

    for (int it = wave; it < 64; it += 4) {
        const int k = it >> 5, rsub = it & 31;
        const long kr = (long)u*1024 + k*512 + rsub*16;

        bf16x8v a0 = *(const bf16x8v*)(Ka + (kr + li)*1024 + h*64 + lg*8);
        bf16x8v a1 = *(const bf16x8v*)(Ka + (kr + li)*1024 + h*64 + 32 + lg*8);
        s16x4 va[4];
        #pragma unroll
        for (int et = 0; et < 4; et++)
            va[et] = *(const s16x4*)(Vt + (long)(h*64 + et*16 + li)*32768 + kr + lg*4);

        f32x4 s[4];
        #pragma unroll
        for (int qt = 0; qt < 4; qt++) {
            f32x4 c = {};
            c = __builtin_amdgcn_mfma_f32_16x16x32_bf16(a0, qf[qt][0], c, 0, 0, 0);
            c = __builtin_amdgcn_mfma_f32_16x16x32_bf16(a1, qf[qt][1], c, 0, 0, 0);
            s[qt] = c;
        }
        float p[4][4];
        #pragma unroll
        for (int qt = 0; qt < 4; qt++)
            #pragma unroll
            for (int j = 0; j < 4; j++)
                p[qt][j] = __builtin_amdgcn_exp2f(s[qt][j]);
        float rz[4];
        #pragma unroll
        for (int j = 0; j < 4; j++) {
            float z = p[0][j] + p[1][j] + p[2][j] + p[3][j];
            z += __shfl_xor(z, 1); z += __shfl_xor(z, 2);
            z += __shfl_xor(z, 4); z += __shfl_xor(z, 8);
            rz[j] = __builtin_amdgcn_rcpf(z);
        }
        s16x4 wf[4];
        #pragma unroll
        for (int qt = 0; qt < 4; qt++) {
            bf16x4v w;
            #pragma unroll
            for (int j = 0; j < 4; j++) w[j] = (__bf16)(p[qt][j] * rz[j]);
            wf[qt] = __builtin_bit_cast(s16x4, w);
        }
        #pragma unroll
        for (int et = 0; et < 4; et++)
            #pragma unroll
            for (int qt = 0; qt < 4; qt++)
                acc[et][qt] = __builtin_amdgcn_mfma_f32_16x16x16bf16_1k(
                    va[et], wf[qt], acc[et][qt], 0, 0, 0);
    }

    __shared__ float Osum[64*64];
    for (int w = 0; w < 4; w++) {
        if (wave == w) {
            #pragma unroll
            for (int et = 0; et < 4; et++)
                #pragma unroll
                for (int qt = 0; qt < 4; qt++)
                    #pragma unroll
                    for (int j = 0; j < 4; j++) {
                        int e = et*16 + lg*4 + j, q = qt*16 + li;
                        if (w == 0) Osum[e*64 + q]  = acc[et][qt][j];
                        else        Osum[e*64 + q] += acc[et][qt][j];
                    }
        }
        __syncthreads();
    }
    const int q = tid & 63, e0 = (tid >> 6) * 16;
    u16x8 o0, o1;
    #pragma unroll
    for (int i = 0; i < 8; i++) {
        o0[i] = f2b(0.5f * Osum[(e0 + i    )*64 + q]);
        o1[i] = f2b(0.5f * Osum[(e0 + 8 + i)*64 + q]);
    }
    u16* dst = Om + (long)(u*64 + q)*1024 + h*64 + e0;
    *(u16x8*)dst       = o0;
    *(u16x8*)(dst + 8) = o1;
}

// ---------------------------------------------------------------------------
// merged f32->bf16 converts: weights (Wq scaled) + optionally nb and x.
// ---------------------------------------------------------------------------
__global__ __launch_bounds__(256)
void convert_all(const float* __restrict__ Wq, const float* __restrict__ Wk,
                 const float* __restrict__ Wv, const float* __restrict__ Wo,
                 const float* __restrict__ nb, const float* __restrict__ x,
                 u16* __restrict__ wW, u16* __restrict__ Anb,
                 u16* __restrict__ xb, int doA)
{
    const int NW = 524288, NN = 4194304, NX = 262144;
    const int tot = doA ? (NW + NN + NX) : NW;
    const int stride = gridDim.x*256;
    for (int i = blockIdx.x*256 + threadIdx.x; i < tot; i += stride) {
        const float* s; u16* d; float sc = 1.0f;
        if (i < NW) {
            int w = i >> 17;
            long off = (long)(i & 131071) * 8;
            s = (w == 0) ? Wq : (w == 1) ? Wk : (w == 2) ? Wv : Wo;
            s += off;
            d = wW + (long)w*1048576 + off;
            if (w == 0) sc = SCALE_LOG2E;
        } else if (i < NW + NN) {
            long off = (long)(i - NW) * 8;
            s = nb + off; d = Anb + off;
        } else {
            long off = (long)(i - NW - NN) * 8;
            s = x + off; d = xb + off;
        }
        float4 f0 = ((const float4*)s)[0], f1 = ((const float4*)s)[1];
        u16x8 o = { f2b(f0.x*sc), f2b(f0.y*sc), f2b(f0.z*sc), f2b(f0.w*sc),
                    f2b(f1.x*sc), f2b(f1.y*sc), f2b(f1.z*sc), f2b(f1.w*sc) };
        *(u16x8*)d = o;
    }
}

__global__ __launch_bounds__(256)
void last_kernel(const u16* __restrict__ Vt, u16* __restrict__ Om)
{
    const int row  = blockIdx.x*4 + (threadIdx.x >> 6);
    const int lane = threadIdx.x & 63;
    const u16* p = Vt + (long)row*32768 + 31*1024 + lane*16;
    float s = 0.f;
    #pragma unroll
    for (int hf = 0; hf < 2; hf++) {
        bf16x8v v = *(const bf16x8v*)(p + hf*8);
        #pragma unroll
        for (int i = 0; i < 8; i++) s += (float)v[i];
    }
    #pragma unroll
    for (int m = 1; m < 64; m <<= 1) s += __shfl_xor(s, m);
    if (lane == 0) Om[(long)1984*1024 + row] = f2b(0.5f * s);
}

__global__ __launch_bounds__(256)
void copy_head(const float* __restrict__ x, float* __restrict__ out)
{
    int i = blockIdx.x*256 + threadIdx.x;
    ((float4*)out)[i] = ((const float4*)x)[i];
}

// ---------------------------------------------------------------------------
extern "C" void kernel_launch(void* const* d_in, const int* in_sizes, int n_in,
                              void* d_out, int out_size, void* d_ws, size_t ws_size,
                              hipStream_t stream)
{
    const float* x  = (const float*)d_in[0];
    const float* nb = (const float*)d_in[1];
    const float* Wq = (const float*)d_in[2];
    const float* Wk = (const float*)d_in[3];
    const float* Wv = (const float*)d_in[4];
    const float* Wo = (const float*)d_in[5];
    float* out = (float*)d_out;
    char*  ws  = (char*)d_ws;

    // ws layout:
    //  [0,8MB)     : bf16 weights Wq(scaled),Wk,Wv,Wo (Wk:Wv contiguous = fused B)
    //  [8,12MB)    : Qa  2048x1024 bf16
    //  [12,16MB)   : Om  2048x1024 bf16 (rows 0..1984 used)
    //  [16,80MB)   : Ka  32768x1024 bf16
    //  [80,144MB)  : Vt  1024x32768 bf16
    //  [144,208MB) : Anb 32768x1024 bf16   (fast path only)
    //  [208,212MB) : xb  2048x1024 bf16    (fast path only)
    if (ws_size < (size_t)144*1024*1024) return;
    const bool big = ws_size >= (size_t)212*1024*1024;
    u16* wW  = (u16*)ws;
    u16* Qa  = (u16*)(ws + (size_t) 8*1024*1024);
    u16* Om  = (u16*)(ws + (size_t)12*1024*1024);
    u16* Ka  = (u16*)(ws + (size_t)16*1024*1024);
    u16* Vt  = (u16*)(ws + (size_t)80*1024*1024);
    u16* Anb = (u16*)(ws + (size_t)144*1024*1024);
    u16* xb  = (u16*)(ws + (size_t)208*1024*1024);
    u16* wWq = wW, *wWk = wW + 1048576, *wWo = wW + 3*1048576;

    convert_all<<<dim3(4096), dim3(256), 0, stream>>>(
        Wq, Wk, Wv, Wo, nb, x, wW, Anb, xb, big ? 1 : 0);

    if (big) {
        gemm128<false, 0><<<dim3(128), dim3(256), 0, stream>>>(
            xb, 1024, wWq, 1024, Qa, nullptr, 2048, 1024, 0, 8);
        // fused K+V projection: 32768x2048 in 256x128 tiles, 2 blocks/CU
        gemm256h<3><<<dim3(2048), dim3(256), 0, stream>>>(
            Anb, 1024, wWk, 1024, Ka, Vt, 32768, 1024, 16);
    } else {
        gemm128<true, 0><<<dim3(128), dim3(256), 0, stream>>>(
            x, 1024, wWq, 1024, Qa, nullptr, 2048, 1024, 0, 8);
        gemm128<true, 3><<<dim3(4096), dim3(256), 0, stream>>>(
            nb, 1024, wWk, 1024, Ka, Vt, 32768, 1024, 0, 16);
    }

    attn_kernel<<<dim3(31, 16), dim3(256), 0, stream>>>(Qa, Ka, Vt, Om);
    last_kernel<<<dim3(256),    dim3(256), 0, stream>>>(Vt, Om);

    gemm128<false, 2><<<dim3(128), dim3(256), 0, stream>>>(
        Om, 1024, wWo, 1024, out, nullptr, 1985, 1024, 63, 8);
    copy_head<<<dim3(63), dim3(256), 0, stream>>>(x, out);
}

// Round 16
// 256.495 us; speedup vs baseline: 1.0826x; 1.0826x over previous
//
#include <hip/hip_runtime.h>
#include <hip/hip_bf16.h>

// ChunkedCrossAttention (RETRO-style), MI355X gfx950.
// N=2048 M=64 K=2 R=512 D=1024 H=16 DH=64 LCH=32
//
// Round 16: revert to round-10 configuration (best measured: 257.0us;
// KV GEMM ~157us @ 37% MfmaUtil). Rounds 11-15 experiments (occupancy play,
// k-split attn, B-from-L2, 64B swizzle) all regressed or were null and are
// dropped. Only change vs r10: last_kernel+copy_head merged into tail_kernel.

using u16 = unsigned short;
using u32 = unsigned int;

typedef float  f32x4   __attribute__((ext_vector_type(4)));
typedef __bf16 bf16x8v __attribute__((ext_vector_type(8)));
typedef __bf16 bf16x4v __attribute__((ext_vector_type(4)));
typedef short  s16x4   __attribute__((ext_vector_type(4)));
typedef u16    u16x8   __attribute__((ext_vector_type(8)));
typedef u16    u16x4v  __attribute__((ext_vector_type(4)));

#define SCALE_LOG2E (1.4426950408889634f / 32.0f)

__device__ __forceinline__ u16 f2b(float f){ return __builtin_bit_cast(u16, (__bf16)f); }
// XOR swizzle on 16B slots within 128B LDS rows
__device__ __forceinline__ int swz(int row, int cb){ return row*128 + (cb ^ ((row & 7) << 4)); }

// async global->LDS, 16B per lane, wave-uniform LDS base (guide §5 / m97)
__device__ __forceinline__ void gl_lds16(const void* g, void* l) {
    __builtin_amdgcn_global_load_lds(
        (const __attribute__((address_space(1))) unsigned int*)(unsigned long long)g,
        (__attribute__((address_space(3))) unsigned int*)(unsigned int)(unsigned long long)l,
        16, 0, 0);
}

// ===========================================================================
// 256x256 GEMM (KV projection) — round-10 version (best measured).
// C(MxN) = A(MxKc) @ B(NxKc)^T, bf16. REQUIRES M,N % 256 == 0.
// 512 threads = 8 waves (2M x 4N), per-wave 128x64 output, BK=64, NT=Kc/64.
// LDS 128KB: A dbuf[2] x half[2] x 16KB at [0,64K); B same at [64K,128K).
// Per tile: 2 barriers, issue-ahead ds_reads with compiler-counted lgkm,
// register-reused operand sets, precomputed per-lane stage pointers.
// ===========================================================================
template<int OM>
__global__ __launch_bounds__(512, 2)
void gemm256(const u16* __restrict__ Ap, int lda,
             const u16* __restrict__ Bp, int ldb,
             void* __restrict__ Cp, void* __restrict__ Cp2,
             int M, int Kc, int nNt)
{
    __shared__ char Ls[131072];
    char* const Abase = Ls;
    char* const Bbase = Ls + 65536;

    const int tid  = threadIdx.x;
    const int lane = tid & 63, wave = tid >> 6;
    const int li = lane & 15, lg = lane >> 4;
    const int wr = wave >> 2, wc = wave & 3;

    const int nwg  = gridDim.x;
    const int lin  = blockIdx.x;
    const int lin2 = (lin & 7) * (nwg >> 3) + (lin >> 3);   // XCD chunk swizzle
    const long bm = (long)(lin2 / nNt) * 256;
    const long bn = (long)(lin2 % nNt) * 256;

    const int srow = tid >> 3;                         // 0..63
    const int scol = ((tid & 7) ^ (srow & 7)) << 3;    // pre-swizzled col (elems)

    const u16* const pA0 = Ap + (bm + srow)*(long)lda + scol;
    const u16* const pA1 = Ap + (bm + 128 + srow)*(long)lda + scol;
    const u16* const pB0 = Bp + (bn + srow)*(long)ldb + scol;
    const u16* const pB1 = Bp + (bn + 128 + srow)*(long)ldb + scol;
    const long l64a = 64*(long)lda, l64b = 64*(long)ldb;

    auto stA = [&](int t, int hh) {
        char* d = Abase + (t & 1)*32768 + hh*16384 + wave*1024;
        const u16* p = (hh ? pA1 : pA0) + (long)t*64;
        gl_lds16(p, d);
        gl_lds16(p + l64a, d + 8192);
    };
    auto stB = [&](int t, int hh) {
        char* d = Bbase + (t & 1)*32768 + hh*16384 + wave*1024;
        const u16* p = (hh ? pB1 : pB0) + (long)t*64;
        gl_lds16(p, d);
        gl_lds16(p + l64b, d + 8192);
    };

    const int NT = Kc >> 6;

    // prologue: tile0 (8 loads) + B0(1) (2) = 10; vmcnt(2) -> tile0 landed
    stB(0, 0); stB(0, 1); stA(0, 0); stA(0, 1); stB(1, 0);
    asm volatile("s_waitcnt vmcnt(2)" ::: "memory");
    asm volatile("s_barrier" ::: "memory");

    const int swx = (li & 7) << 4;
    const int cb0 = (lg*16) ^ swx;          // k-step 0 column bytes (swizzled)
    const int cb1 = (64 + lg*16) ^ swx;     // k-step 1
    const int brb = (wc & 1)*64 + li;       // B row within wc>>1 half

    f32x4 acc[8][4] = {};
    bf16x8v av[4], aw[4], bv[4];

#define MFMA16(MH, AA, BB)                                                      \
    __builtin_amdgcn_s_setprio(1);                                              \
    _Pragma("unroll") for (int mt = 0; mt < 4; mt++)                            \
        _Pragma("unroll") for (int nt = 0; nt < 4; nt++)                        \
            acc[(MH)*4 + mt][nt] = __builtin_amdgcn_mfma_f32_16x16x32_bf16(     \
                (AA)[mt], (BB)[nt], acc[(MH)*4 + mt][nt], 0, 0, 0);             \
    __builtin_amdgcn_s_setprio(0);
#define RDA(DST, OFS, CB)                                                       \
    _Pragma("unroll") for (int i = 0; i < 4; i++)                               \
        (DST)[i] = *(const bf16x8v*)(At + (li + (OFS) + i*16)*128 + (CB));
#define RDB(DST, CB)                                                            \
    _Pragma("unroll") for (int i = 0; i < 4; i++)                               \
        (DST)[i] = *(const bf16x8v*)(Bt + (brb + i*16)*128 + (CB));

    for (int t = 0; t < NT; ++t) {
        char* At = Abase + (t & 1)*32768 + wr*16384;
        char* Bt = Bbase + (t & 1)*32768 + (wc >> 1)*16384;
        const bool s1 = (t + 1 < NT), s2 = (t + 2 < NT);

        RDA(av, 0, cb0); RDB(bv, cb0);
        if (s1) { stB(t + 1, 1); stA(t + 1, 0); }
        RDA(aw, 64, cb0);
        __builtin_amdgcn_sched_barrier(0);
        MFMA16(0, av, bv);
        if (s1) stA(t + 1, 1);
        RDA(av, 0, cb1);
        __builtin_amdgcn_sched_barrier(0);
        MFMA16(1, aw, bv);
        RDB(bv, cb1); RDA(aw, 64, cb1);
        __builtin_amdgcn_sched_barrier(0);
        MFMA16(0, av, bv);
        asm volatile("s_barrier" ::: "memory");   // MID: all waves' b@k1 reads done
        if (s2) stB(t + 2, 0);
        MFMA16(1, aw, bv);
        if      (s2) { asm volatile("s_waitcnt vmcnt(2)" ::: "memory"); }
        else if (s1) { asm volatile("s_waitcnt vmcnt(0)" ::: "memory"); }
        asm volatile("s_barrier" ::: "memory");   // END: publish t+1 stages
    }
#undef MFMA16
#undef RDA
#undef RDB

    if (OM == 3 && bn >= 1024) {
        // --- V-block epilogue: LDS transpose -> coalesced Vt stores ---
        u16* Vt = (u16*)Cp2;
        #pragma unroll
        for (int ai = 0; ai < 8; ai++) {
            const int m0 = wr*128 + (ai >> 2)*64 + (ai & 3)*16 + lg*4;   // 4-aligned
            #pragma unroll
            for (int nt = 0; nt < 4; nt++) {
                const int n = wc*64 + nt*16 + li;
                f32x4 c = acc[ai][nt];
                bf16x4v w;
                #pragma unroll
                for (int j = 0; j < 4; j++) w[j] = (__bf16)c[j];
                *(bf16x4v*)(Ls + n*512 + ((m0*2) ^ ((n & 31) << 4))) = w;
            }
        }
        __syncthreads();
        const int n    = tid >> 1;              // Vt-local row 0..255
        const int half = (tid & 1) * 128;       // m half
        u16* dst = Vt + (bn - 1024 + n)*32768L + bm + half;
        #pragma unroll
        for (int i = 0; i < 16; i++) {
            const int mb = (half + i*8) * 2;    // byte offset, 16B aligned
            uint4 v = *(const uint4*)(Ls + n*512 + (mb ^ ((n & 31) << 4)));
            *(uint4*)(dst + i*8) = v;
        }
    } else if (OM == 3) {
        // --- K-block epilogue: row-major 2B stores ---
        u16* Ka = (u16*)Cp;
        #pragma unroll
        for (int ai = 0; ai < 8; ai++) {
            #pragma unroll
            for (int nt = 0; nt < 4; nt++) {
                f32x4 c = acc[ai][nt];
                const long row0 = bm + wr*128 + (ai >> 2)*64 + (ai & 3)*16 + lg*4;
                const long col  = bn + wc*64 + nt*16 + li;
                #pragma unroll
                for (int j = 0; j < 4; j++)
                    Ka[(row0 + j)*1024 + col] = f2b(c[j]);
            }
        }
    }
}

// ---------------------------------------------------------------------------
// 128x128x64-step GEMM (Q/Wo projections + fallback), unchanged.
// ---------------------------------------------------------------------------
template<bool AF32, int OM>
__global__ __launch_bounds__(256)
void gemm128(const void* __restrict__ Ap, int lda,
             const u16* __restrict__ Bp, int ldb,
             void* __restrict__ Cp, void* __restrict__ Cp2,
             int M, int Kc, int row_off, int nNt)
{
    __shared__ char As[128*128];
    __shared__ char Bs[128*128];
    const int tid  = threadIdx.x;
    const int lane = tid & 63, wave = tid >> 6;
    const int li = lane & 15, lg = lane >> 4;
    const int wr = wave >> 1, wc = wave & 1;

    const int nwg  = gridDim.x;
    const int lin  = blockIdx.x;
    const int lin2 = (lin & 7) * (nwg >> 3) + (lin >> 3);
    const long bm = (long)(lin2 / nNt) * 128;
    const long bn = (long)(lin2 % nNt) * 128;

    const int grow = wave*32 + (lane >> 3);
    const int gcol = ((lane & 7) ^ (lane >> 3)) << 3;
    const int sr = tid >> 1, sc = (tid & 1) * 32;
    long arow_f = bm + sr; if (arow_f >= M) arow_f = M - 1;
    long arow_g[4];
    #pragma unroll
    for (int j = 0; j < 4; j++) {
        long r = bm + grow + j*8;
        arow_g[j] = (r < M) ? r : (M - 1);
    }

    f32x4 acc[4][4] = {};

    for (int k0 = 0; k0 < Kc; k0 += 64) {
        float4 a4[8];
        if (AF32) {
            const float4* ap = (const float4*)((const float*)Ap + arow_f*lda + k0 + sc);
            #pragma unroll
            for (int i = 0; i < 8; i++) a4[i] = ap[i];
        }
        __syncthreads();
        if (!AF32) {
            #pragma unroll
            for (int j = 0; j < 4; j++)
                gl_lds16((const u16*)Ap + arow_g[j]*(long)lda + k0 + gcol,
                         As + (wave*4 + j)*1024);
        }
        #pragma unroll
        for (int j = 0; j < 4; j++)
            gl_lds16(Bp + (bn + grow + j*8)*(long)ldb + k0 + gcol,
                     Bs + (wave*4 + j)*1024);
        if (AF32) {
            #pragma unroll
            for (int i = 0; i < 4; i++) {
                float4 f0 = a4[2*i], f1 = a4[2*i+1];
                bf16x8v w;
                w[0]=(__bf16)f0.x; w[1]=(__bf16)f0.y; w[2]=(__bf16)f0.z; w[3]=(__bf16)f0.w;
                w[4]=(__bf16)f1.x; w[5]=(__bf16)f1.y; w[6]=(__bf16)f1.z; w[7]=(__bf16)f1.w;
                *(bf16x8v*)(As + swz(sr, sc*2 + i*16)) = w;
            }
        }
        __syncthreads();
        #pragma unroll
        for (int es = 0; es < 2; es++) {
            bf16x8v af[4], bfv[4];
            #pragma unroll
            for (int mt = 0; mt < 4; mt++)
                af[mt] = *(const bf16x8v*)(As + swz(wr*64 + mt*16 + li, es*64 + lg*16));
            #pragma unroll
            for (int nt = 0; nt < 4; nt++)
                bfv[nt] = *(const bf16x8v*)(Bs + swz(wc*64 + nt*16 + li, es*64 + lg*16));
            #pragma unroll
            for (int mt = 0; mt < 4; mt++)
                #pragma unroll
                for (int nt = 0; nt < 4; nt++)
                    acc[mt][nt] = __builtin_amdgcn_mfma_f32_16x16x32_bf16(
                        af[mt], bfv[nt], acc[mt][nt], 0, 0, 0);
        }
    }

    #pragma unroll
    for (int mt = 0; mt < 4; mt++) {
        #pragma unroll
        for (int nt = 0; nt < 4; nt++) {
            f32x4 c = acc[mt][nt];
            const long row0 = bm + wr*64 + mt*16 + lg*4;
            const long col  = bn + wc*64 + nt*16 + li;
            if (OM == 0) {
                u16* C = (u16*)Cp;
                #pragma unroll
                for (int j = 0; j < 4; j++) {
                    long rg = row0 + j;
                    if (rg < M) C[rg*1024 + col] = f2b(c[j]);
                }
            } else if (OM == 2) {
                float* C = (float*)Cp;
                #pragma unroll
                for (int j = 0; j < 4; j++) {
                    long rg = row0 + j;
                    if (rg < M) C[(row_off + rg)*1024 + col] = c[j];
                }
            } else {
                if (col < 1024) {
                    u16* Ka = (u16*)Cp;
                    #pragma unroll
                    for (int j = 0; j < 4; j++) Ka[(row0 + j)*1024 + col] = f2b(c[j]);
                } else {
                    u16* Vt = (u16*)Cp2;
                    bf16x4v w;
                    #pragma unroll
                    for (int j = 0; j < 4; j++) w[j] = (__bf16)c[j];
                    *(bf16x4v*)(Vt + (col - 1024)*32768L + row0) = w;
                }
            }
        }
    }
}

// ---------------------------------------------------------------------------
// Fused attention: grid (31, 16), 4 waves stride 64 substeps (r10 best).
// ---------------------------------------------------------------------------
__global__ __launch_bounds__(256)
void attn_kernel(const u16* __restrict__ Qa, const u16* __restrict__ Ka,
                 const u16* __restrict__ Vt, u16* __restrict__ Om)
{
    const int u = blockIdx.x, h = blockIdx.y;
    const int tid = threadIdx.x;
    const int lane = tid & 63, wave = tid >> 6;
    const int li = lane & 15, lg = lane >> 4;

    bf16x8v qf[4][2];
    #pragma unroll
    for (int qt = 0; qt < 4; qt++)
        #pragma unroll
        for (int es = 0; es < 2; es++)
            qf[qt][es] = *(const bf16x8v*)(Qa + (long)(63 + u*64 + qt*16 + li)*1024
                                              + h*64 + es*32 + lg*8);

    f32x4 acc[4][4] = {};

    for (int it = wave; it < 64; it += 4) {
        const int k = it >> 5, rsub = it & 31;
        const long kr = (long)u*1024 + k*512 + rsub*16;

        bf16x8v a0 = *(const bf16x8v*)(Ka + (kr + li)*1024 + h*64 + lg*8);
        bf16x8v a1 = *(const bf16x8v*)(Ka + (kr + li)*1024 + h*64 + 32 + lg*8);
        s16x4 va[4];
        #pragma unroll
        for (int et = 0; et < 4; et++)
            va[et] = *(const s16x4*)(Vt + (long)(h*64 + et*16 + li)*32768 + kr + lg*4);

        f32x4 s[4];
        #pragma unroll
        for (int qt = 0; qt < 4; qt++) {
            f32x4 c = {};
            c = __builtin_amdgcn_mfma_f32_16x16x32_bf16(a0, qf[qt][0], c, 0, 0, 0);
            c = __builtin_amdgcn_mfma_f32_16x16x32_bf16(a1, qf[qt][1], c, 0, 0, 0);
            s[qt] = c;
        }
        float p[4][4];
        #pragma unroll
        for (int qt = 0; qt < 4; qt++)
            #pragma unroll
            for (int j = 0; j < 4; j++)
                p[qt][j] = __builtin_amdgcn_exp2f(s[qt][j]);
        float rz[4];
        #pragma unroll
        for (int j = 0; j < 4; j++) {
            float z = p[0][j] + p[1][j] + p[2][j] + p[3][j];
            z += __shfl_xor(z, 1); z += __shfl_xor(z, 2);
            z += __shfl_xor(z, 4); z += __shfl_xor(z, 8);
            rz[j] = __builtin_amdgcn_rcpf(z);
        }
        s16x4 wf[4];
        #pragma unroll
        for (int qt = 0; qt < 4; qt++) {
            bf16x4v w;
            #pragma unroll
            for (int j = 0; j < 4; j++) w[j] = (__bf16)(p[qt][j] * rz[j]);
            wf[qt] = __builtin_bit_cast(s16x4, w);
        }
        #pragma unroll
        for (int et = 0; et < 4; et++)
            #pragma unroll
            for (int qt = 0; qt < 4; qt++)
                acc[et][qt] = __builtin_amdgcn_mfma_f32_16x16x16bf16_1k(
                    va[et], wf[qt], acc[et][qt], 0, 0, 0);
    }

    __shared__ float Osum[64*64];
    for (int w = 0; w < 4; w++) {
        if (wave == w) {
            #pragma unroll
            for (int et = 0; et < 4; et++)
                #pragma unroll
                for (int qt = 0; qt < 4; qt++)
                    #pragma unroll
                    for (int j = 0; j < 4; j++) {
                        int e = et*16 + lg*4 + j, q = qt*16 + li;
                        if (w == 0) Osum[e*64 + q]  = acc[et][qt][j];
                        else        Osum[e*64 + q] += acc[et][qt][j];
                    }
        }
        __syncthreads();
    }
    const int q = tid & 63, e0 = (tid >> 6) * 16;
    u16x8 o0, o1;
    #pragma unroll
    for (int i = 0; i < 8; i++) {
        o0[i] = f2b(0.5f * Osum[(e0 + i    )*64 + q]);
        o1[i] = f2b(0.5f * Osum[(e0 + 8 + i)*64 + q]);
    }
    u16* dst = Om + (long)(u*64 + q)*1024 + h*64 + e0;
    *(u16x8*)dst       = o0;
    *(u16x8*)(dst + 8) = o1;
}

// ---------------------------------------------------------------------------
// merged f32->bf16 converts: weights (Wq scaled) + optionally nb and x.
// ---------------------------------------------------------------------------
__global__ __launch_bounds__(256)
void convert_all(const float* __restrict__ Wq, const float* __restrict__ Wk,
                 const float* __restrict__ Wv, const float* __restrict__ Wo,
                 const float* __restrict__ nb, const float* __restrict__ x,
                 u16* __restrict__ wW, u16* __restrict__ Anb,
                 u16* __restrict__ xb, int doA)
{
    const int NW = 524288, NN = 4194304, NX = 262144;
    const int tot = doA ? (NW + NN + NX) : NW;
    const int stride = gridDim.x*256;
    for (int i = blockIdx.x*256 + threadIdx.x; i < tot; i += stride) {
        const float* s; u16* d; float sc = 1.0f;
        if (i < NW) {
            int w = i >> 17;
            long off = (long)(i & 131071) * 8;
            s = (w == 0) ? Wq : (w == 1) ? Wk : (w == 2) ? Wv : Wo;
            s += off;
            d = wW + (long)w*1048576 + off;
            if (w == 0) sc = SCALE_LOG2E;
        } else if (i < NW + NN) {
            long off = (long)(i - NW) * 8;
            s = nb + off; d = Anb + off;
        } else {
            long off = (long)(i - NW - NN) * 8;
            s = x + off; d = xb + off;
        }
        float4 f0 = ((const float4*)s)[0], f1 = ((const float4*)s)[1];
        u16x8 o = { f2b(f0.x*sc), f2b(f0.y*sc), f2b(f0.z*sc), f2b(f0.w*sc),
                    f2b(f1.x*sc), f2b(f1.y*sc), f2b(f1.z*sc), f2b(f1.w*sc) };
        *(u16x8*)d = o;
    }
}

// ---------------------------------------------------------------------------
// tail: blocks 0..255 = last-token row sums (Q=1 softmax => w==1);
//       blocks 256..318 = copy out[0:63] = x[0:63].
// ---------------------------------------------------------------------------
__global__ __launch_bounds__(256)
void tail_kernel(const u16* __restrict__ Vt, u16* __restrict__ Om,
                 const float* __restrict__ x, float* __restrict__ out)
{
    if (blockIdx.x < 256) {
        const int row  = blockIdx.x*4 + (threadIdx.x >> 6);   // 0..1023
        const int lane = threadIdx.x & 63;
        const u16* p = Vt + (long)row*32768 + 31*1024 + lane*16;
        float s = 0.f;
        #pragma unroll
        for (int hf = 0; hf < 2; hf++) {
            bf16x8v v = *(const bf16x8v*)(p + hf*8);
            #pragma unroll
            for (int i = 0; i < 8; i++) s += (float)v[i];
        }
        #pragma unroll
        for (int m = 1; m < 64; m <<= 1) s += __shfl_xor(s, m);
        if (lane == 0) Om[(long)1984*1024 + row] = f2b(0.5f * s);
    } else {
        int i = (blockIdx.x - 256)*256 + threadIdx.x;   // 63*256 float4s
        ((float4*)out)[i] = ((const float4*)x)[i];
    }
}

// ---------------------------------------------------------------------------
extern "C" void kernel_launch(void* const* d_in, const int* in_sizes, int n_in,
                              void* d_out, int out_size, void* d_ws, size_t ws_size,
                              hipStream_t stream)
{
    const float* x  = (const float*)d_in[0];
    const float* nb = (const float*)d_in[1];
    const float* Wq = (const float*)d_in[2];
    const float* Wk = (const float*)d_in[3];
    const float* Wv = (const float*)d_in[4];
    const float* Wo = (const float*)d_in[5];
    float* out = (float*)d_out;
    char*  ws  = (char*)d_ws;

    // ws layout:
    //  [0,8MB)     : bf16 weights Wq(scaled),Wk,Wv,Wo (Wk:Wv contiguous = fused B)
    //  [8,12MB)    : Qa  2048x1024 bf16
    //  [12,16MB)   : Om  2048x1024 bf16 (rows 0..1984 used)
    //  [16,80MB)   : Ka  32768x1024 bf16
    //  [80,144MB)  : Vt  1024x32768 bf16
    //  [144,208MB) : Anb 32768x1024 bf16   (fast path only)
    //  [208,212MB) : xb  2048x1024 bf16    (fast path only)
    if (ws_size < (size_t)144*1024*1024) return;
    const bool big = ws_size >= (size_t)212*1024*1024;
    u16* wW  = (u16*)ws;
    u16* Qa  = (u16*)(ws + (size_t) 8*1024*1024);
    u16* Om  = (u16*)(ws + (size_t)12*1024*1024);
    u16* Ka  = (u16*)(ws + (size_t)16*1024*1024);
    u16* Vt  = (u16*)(ws + (size_t)80*1024*1024);
    u16* Anb = (u16*)(ws + (size_t)144*1024*1024);
    u16* xb  = (u16*)(ws + (size_t)208*1024*1024);
    u16* wWq = wW, *wWk = wW + 1048576, *wWo = wW + 3*1048576;

    convert_all<<<dim3(4096), dim3(256), 0, stream>>>(
        Wq, Wk, Wv, Wo, nb, x, wW, Anb, xb, big ? 1 : 0);

    if (big) {
        gemm128<false, 0><<<dim3(128), dim3(256), 0, stream>>>(
            xb, 1024, wWq, 1024, Qa, nullptr, 2048, 1024, 0, 8);
        // fused K+V projection: 32768x2048, 128x8 256-tiles
        gemm256<3><<<dim3(1024), dim3(512), 0, stream>>>(
            Anb, 1024, wWk, 1024, Ka, Vt, 32768, 1024, 8);
    } else {
        gemm128<true, 0><<<dim3(128), dim3(256), 0, stream>>>(
            x, 1024, wWq, 1024, Qa, nullptr, 2048, 1024, 0, 8);
        gemm128<true, 3><<<dim3(4096), dim3(256), 0, stream>>>(
            nb, 1024, wWk, 1024, Ka, Vt, 32768, 1024, 0, 16);
    }

    attn_kernel<<<dim3(31, 16), dim3(256), 0, stream>>>(Qa, Ka, Vt, Om);
    tail_kernel<<<dim3(319), dim3(256), 0, stream>>>(Vt, Om, x, out);

    gemm128<false, 2><<<dim3(128), dim3(256), 0, stream>>>(
        Om, 1024, wWo, 1024, out, nullptr, 1985, 1024, 63, 8);
}

// Round 17
// 246.660 us; speedup vs baseline: 1.1258x; 1.0399x over previous
//
#include <hip/hip_runtime.h>
#include <hip/hip_bf16.h>

// ChunkedCrossAttention (RETRO-style), MI355X gfx950.
// N=2048 M=64 K=2 R=512 D=1024 H=16 DH=64 LCH=32
//
// Round 17: r16 (= r10 best config) + Q projection merged into the KV
// gemm256 dispatch as 32 extra 256x256-tile blocks (same K-loop, Q epilogue
// = row-major store to Qa). Saves the separate 10us Q dispatch + 1 launch.

using u16 = unsigned short;
using u32 = unsigned int;

typedef float  f32x4   __attribute__((ext_vector_type(4)));
typedef __bf16 bf16x8v __attribute__((ext_vector_type(8)));
typedef __bf16 bf16x4v __attribute__((ext_vector_type(4)));
typedef short  s16x4   __attribute__((ext_vector_type(4)));
typedef u16    u16x8   __attribute__((ext_vector_type(8)));
typedef u16    u16x4v  __attribute__((ext_vector_type(4)));

#define SCALE_LOG2E (1.4426950408889634f / 32.0f)

__device__ __forceinline__ u16 f2b(float f){ return __builtin_bit_cast(u16, (__bf16)f); }
// XOR swizzle on 16B slots within 128B LDS rows
__device__ __forceinline__ int swz(int row, int cb){ return row*128 + (cb ^ ((row & 7) << 4)); }

// async global->LDS, 16B per lane, wave-uniform LDS base (guide §5 / m97)
__device__ __forceinline__ void gl_lds16(const void* g, void* l) {
    __builtin_amdgcn_global_load_lds(
        (const __attribute__((address_space(1))) unsigned int*)(unsigned long long)g,
        (__attribute__((address_space(3))) unsigned int*)(unsigned int)(unsigned long long)l,
        16, 0, 0);
}

// ===========================================================================
// 256x256 GEMM, r10 K-loop (best measured). Dual-problem dispatch:
//   lin2 <  nKV : KV blocks  — A=Ap(Anb), B=Bp(wWk:wWv), epilogue Ka / Vt^T
//   lin2 >= nKV : Q  blocks  — A=Aq(xb),  B=Bq(wWq),     epilogue Qa row-major
// All dims multiples of 256 (KV: 32768x2048; Q: 2048x1024), Kc=1024 both.
// 512 threads = 8 waves (2M x 4N), per-wave 128x64 output, BK=64, NT=16.
// LDS 128KB: A dbuf[2] x half[2] x 16KB at [0,64K); B same at [64K,128K).
// Per tile: 2 barriers, issue-ahead ds_reads (compiler-counted lgkm),
// register-reused operands, precomputed per-lane stage pointers, counted
// vmcnt(2) at MID/END (r10 schedule, verified).
// ===========================================================================
__global__ __launch_bounds__(512, 2)
void gemm256(const u16* __restrict__ Ap, const u16* __restrict__ Bp,
             u16* __restrict__ Ka, u16* __restrict__ Vt,
             const u16* __restrict__ Aq, const u16* __restrict__ Bq,
             u16* __restrict__ Qa,
             int nKV, int nNt)
{
    __shared__ char Ls[131072];
    char* const Abase = Ls;
    char* const Bbase = Ls + 65536;

    const int tid  = threadIdx.x;
    const int lane = tid & 63, wave = tid >> 6;
    const int li = lane & 15, lg = lane >> 4;
    const int wr = wave >> 2, wc = wave & 3;

    const int nwg  = gridDim.x;
    const int lin  = blockIdx.x;
    const int lin2 = (lin & 7) * (nwg >> 3) + (lin >> 3);   // XCD chunk swizzle

    const bool isQ = (lin2 >= nKV);
    long bm, bn;
    if (isQ) { const int idx = lin2 - nKV; bm = (long)(idx >> 2) * 256; bn = (long)(idx & 3) * 256; }
    else     {                              bm = (long)(lin2 / nNt) * 256; bn = (long)(lin2 % nNt) * 256; }
    const u16* const Ag = isQ ? Aq : Ap;    // lda = ldb = 1024 for all
    const u16* const Bg = isQ ? Bq : Bp;

    const int srow = tid >> 3;                         // 0..63
    const int scol = ((tid & 7) ^ (srow & 7)) << 3;    // pre-swizzled col (elems)

    const u16* const pA0 = Ag + (bm + srow)*1024L + scol;
    const u16* const pA1 = Ag + (bm + 128 + srow)*1024L + scol;
    const u16* const pB0 = Bg + (bn + srow)*1024L + scol;
    const u16* const pB1 = Bg + (bn + 128 + srow)*1024L + scol;
    const long l64 = 64*1024L;

    auto stA = [&](int t, int hh) {
        char* d = Abase + (t & 1)*32768 + hh*16384 + wave*1024;
        const u16* p = (hh ? pA1 : pA0) + (long)t*64;
        gl_lds16(p, d);
        gl_lds16(p + l64, d + 8192);
    };
    auto stB = [&](int t, int hh) {
        char* d = Bbase + (t & 1)*32768 + hh*16384 + wave*1024;
        const u16* p = (hh ? pB1 : pB0) + (long)t*64;
        gl_lds16(p, d);
        gl_lds16(p + l64, d + 8192);
    };

    const int NT = 16;   // Kc = 1024 for both problems

    // prologue: tile0 (8 loads) + B0(1) (2) = 10; vmcnt(2) -> tile0 landed
    stB(0, 0); stB(0, 1); stA(0, 0); stA(0, 1); stB(1, 0);
    asm volatile("s_waitcnt vmcnt(2)" ::: "memory");
    asm volatile("s_barrier" ::: "memory");

    const int swx = (li & 7) << 4;
    const int cb0 = (lg*16) ^ swx;          // k-step 0 column bytes (swizzled)
    const int cb1 = (64 + lg*16) ^ swx;     // k-step 1
    const int brb = (wc & 1)*64 + li;       // B row within wc>>1 half

    f32x4 acc[8][4] = {};
    bf16x8v av[4], aw[4], bv[4];

#define MFMA16(MH, AA, BB)                                                      \
    __builtin_amdgcn_s_setprio(1);                                              \
    _Pragma("unroll") for (int mt = 0; mt < 4; mt++)                            \
        _Pragma("unroll") for (int nt = 0; nt < 4; nt++)                        \
            acc[(MH)*4 + mt][nt] = __builtin_amdgcn_mfma_f32_16x16x32_bf16(     \
                (AA)[mt], (BB)[nt], acc[(MH)*4 + mt][nt], 0, 0, 0);             \
    __builtin_amdgcn_s_setprio(0);
#define RDA(DST, OFS, CB)                                                       \
    _Pragma("unroll") for (int i = 0; i < 4; i++)                               \
        (DST)[i] = *(const bf16x8v*)(At + (li + (OFS) + i*16)*128 + (CB));
#define RDB(DST, CB)                                                            \
    _Pragma("unroll") for (int i = 0; i < 4; i++)                               \
        (DST)[i] = *(const bf16x8v*)(Bt + (brb + i*16)*128 + (CB));

    for (int t = 0; t < NT; ++t) {
        char* At = Abase + (t & 1)*32768 + wr*16384;
        char* Bt = Bbase + (t & 1)*32768 + (wc >> 1)*16384;
        const bool s1 = (t + 1 < NT), s2 = (t + 2 < NT);

        RDA(av, 0, cb0); RDB(bv, cb0);
        if (s1) { stB(t + 1, 1); stA(t + 1, 0); }
        RDA(aw, 64, cb0);
        __builtin_amdgcn_sched_barrier(0);
        MFMA16(0, av, bv);
        if (s1) stA(t + 1, 1);
        RDA(av, 0, cb1);
        __builtin_amdgcn_sched_barrier(0);
        MFMA16(1, aw, bv);
        RDB(bv, cb1); RDA(aw, 64, cb1);
        __builtin_amdgcn_sched_barrier(0);
        MFMA16(0, av, bv);
        asm volatile("s_barrier" ::: "memory");   // MID: all waves' b@k1 reads done
        if (s2) stB(t + 2, 0);
        MFMA16(1, aw, bv);
        if      (s2) { asm volatile("s_waitcnt vmcnt(2)" ::: "memory"); }
        else if (s1) { asm volatile("s_waitcnt vmcnt(0)" ::: "memory"); }
        asm volatile("s_barrier" ::: "memory");   // END: publish t+1 stages
    }
#undef MFMA16
#undef RDA
#undef RDB

    if (!isQ && bn >= 1024) {
        // --- V-block epilogue: LDS transpose -> coalesced Vt stores ---
        #pragma unroll
        for (int ai = 0; ai < 8; ai++) {
            const int m0 = wr*128 + (ai >> 2)*64 + (ai & 3)*16 + lg*4;   // 4-aligned
            #pragma unroll
            for (int nt = 0; nt < 4; nt++) {
                const int n = wc*64 + nt*16 + li;
                f32x4 c = acc[ai][nt];
                bf16x4v w;
                #pragma unroll
                for (int j = 0; j < 4; j++) w[j] = (__bf16)c[j];
                *(bf16x4v*)(Ls + n*512 + ((m0*2) ^ ((n & 31) << 4))) = w;
            }
        }
        __syncthreads();
        const int n    = tid >> 1;              // Vt-local row 0..255
        const int half = (tid & 1) * 128;       // m half
        u16* dst = Vt + (bn - 1024 + n)*32768L + bm + half;
        #pragma unroll
        for (int i = 0; i < 16; i++) {
            const int mb = (half + i*8) * 2;    // byte offset, 16B aligned
            uint4 v = *(const uint4*)(Ls + n*512 + (mb ^ ((n & 31) << 4)));
            *(uint4*)(dst + i*8) = v;
        }
    } else {
        // --- row-major 2B stores: Ka (KV, bn<1024) or Qa (Q blocks) ---
        u16* Co = isQ ? Qa : Ka;
        #pragma unroll
        for (int ai = 0; ai < 8; ai++) {
            #pragma unroll
            for (int nt = 0; nt < 4; nt++) {
                f32x4 c = acc[ai][nt];
                const long row0 = bm + wr*128 + (ai >> 2)*64 + (ai & 3)*16 + lg*4;
                const long col  = bn + wc*64 + nt*16 + li;
                #pragma unroll
                for (int j = 0; j < 4; j++)
                    Co[(row0 + j)*1024 + col] = f2b(c[j]);
            }
        }
    }
}

// ---------------------------------------------------------------------------
// 128x128x64-step GEMM (Wo projection + small-ws fallback), unchanged.
// ---------------------------------------------------------------------------
template<bool AF32, int OM>
__global__ __launch_bounds__(256)
void gemm128(const void* __restrict__ Ap, int lda,
             const u16* __restrict__ Bp, int ldb,
             void* __restrict__ Cp, void* __restrict__ Cp2,
             int M, int Kc, int row_off, int nNt)
{
    __shared__ char As[128*128];
    __shared__ char Bs[128*128];
    const int tid  = threadIdx.x;
    const int lane = tid & 63, wave = tid >> 6;
    const int li = lane & 15, lg = lane >> 4;
    const int wr = wave >> 1, wc = wave & 1;

    const int nwg  = gridDim.x;
    const int lin  = blockIdx.x;
    const int lin2 = (lin & 7) * (nwg >> 3) + (lin >> 3);
    const long bm = (long)(lin2 / nNt) * 128;
    const long bn = (long)(lin2 % nNt) * 128;

    const int grow = wave*32 + (lane >> 3);
    const int gcol = ((lane & 7) ^ (lane >> 3)) << 3;
    const int sr = tid >> 1, sc = (tid & 1) * 32;
    long arow_f = bm + sr; if (arow_f >= M) arow_f = M - 1;
    long arow_g[4];
    #pragma unroll
    for (int j = 0; j < 4; j++) {
        long r = bm + grow + j*8;
        arow_g[j] = (r < M) ? r : (M - 1);
    }

    f32x4 acc[4][4] = {};

    for (int k0 = 0; k0 < Kc; k0 += 64) {
        float4 a4[8];
        if (AF32) {
            const float4* ap = (const float4*)((const float*)Ap + arow_f*lda + k0 + sc);
            #pragma unroll
            for (int i = 0; i < 8; i++) a4[i] = ap[i];
        }
        __syncthreads();
        if (!AF32) {
            #pragma unroll
            for (int j = 0; j < 4; j++)
                gl_lds16((const u16*)Ap + arow_g[j]*(long)lda + k0 + gcol,
                         As + (wave*4 + j)*1024);
        }
        #pragma unroll
        for (int j = 0; j < 4; j++)
            gl_lds16(Bp + (bn + grow + j*8)*(long)ldb + k0 + gcol,
                     Bs + (wave*4 + j)*1024);
        if (AF32) {
            #pragma unroll
            for (int i = 0; i < 4; i++) {
                float4 f0 = a4[2*i], f1 = a4[2*i+1];
                bf16x8v w;
                w[0]=(__bf16)f0.x; w[1]=(__bf16)f0.y; w[2]=(__bf16)f0.z; w[3]=(__bf16)f0.w;
                w[4]=(__bf16)f1.x; w[5]=(__bf16)f1.y; w[6]=(__bf16)f1.z; w[7]=(__bf16)f1.w;
                *(bf16x8v*)(As + swz(sr, sc*2 + i*16)) = w;
            }
        }
        __syncthreads();
        #pragma unroll
        for (int es = 0; es < 2; es++) {
            bf16x8v af[4], bfv[4];
            #pragma unroll
            for (int mt = 0; mt < 4; mt++)
                af[mt] = *(const bf16x8v*)(As + swz(wr*64 + mt*16 + li, es*64 + lg*16));
            #pragma unroll
            for (int nt = 0; nt < 4; nt++)
                bfv[nt] = *(const bf16x8v*)(Bs + swz(wc*64 + nt*16 + li, es*64 + lg*16));
            #pragma unroll
            for (int mt = 0; mt < 4; mt++)
                #pragma unroll
                for (int nt = 0; nt < 4; nt++)
                    acc[mt][nt] = __builtin_amdgcn_mfma_f32_16x16x32_bf16(
                        af[mt], bfv[nt], acc[mt][nt], 0, 0, 0);
        }
    }

    #pragma unroll
    for (int mt = 0; mt < 4; mt++) {
        #pragma unroll
        for (int nt = 0; nt < 4; nt++) {
            f32x4 c = acc[mt][nt];
            const long row0 = bm + wr*64 + mt*16 + lg*4;
            const long col  = bn + wc*64 + nt*16 + li;
            if (OM == 0) {
                u16* C = (u16*)Cp;
                #pragma unroll
                for (int j = 0; j < 4; j++) {
                    long rg = row0 + j;
                    if (rg < M) C[rg*1024 + col] = f2b(c[j]);
                }
            } else if (OM == 2) {
                float* C = (float*)Cp;
                #pragma unroll
                for (int j = 0; j < 4; j++) {
                    long rg = row0 + j;
                    if (rg < M) C[(row_off + rg)*1024 + col] = c[j];
                }
            } else {
                if (col < 1024) {
                    u16* Ka = (u16*)Cp;
                    #pragma unroll
                    for (int j = 0; j < 4; j++) Ka[(row0 + j)*1024 + col] = f2b(c[j]);
                } else {
                    u16* Vt = (u16*)Cp2;
                    bf16x4v w;
                    #pragma unroll
                    for (int j = 0; j < 4; j++) w[j] = (__bf16)c[j];
                    *(bf16x4v*)(Vt + (col - 1024)*32768L + row0) = w;
                }
            }
        }
    }
}

// ---------------------------------------------------------------------------
// Fused attention: grid (31, 16), 4 waves stride 64 substeps (r10 best).
// ---------------------------------------------------------------------------
__global__ __launch_bounds__(256)
void attn_kernel(const u16* __restrict__ Qa, const u16* __restrict__ Ka,
                 const u16* __restrict__ Vt, u16* __restrict__ Om)
{
    const int u = blockIdx.x, h = blockIdx.y;
    const int tid = threadIdx.x;
    const int lane = tid & 63, wave = tid >> 6;
    const int li = lane & 15, lg = lane >> 4;

    bf16x8v qf[4][2];
    #pragma unroll
    for (int qt = 0; qt < 4; qt++)
        #pragma unroll
        for (int es = 0; es < 2; es++)
            qf[qt][es] = *(const bf16x8v*)(Qa + (long)(63 + u*64 + qt*16 + li)*1024
                                              + h*64 + es*32 + lg*8);

    f32x4 acc[4][4] = {};

    for (int it = wave; it < 64; it += 4) {
        const int k = it >> 5, rsub = it & 31;
        const long kr = (long)u*1024 + k*512 + rsub*16;

        bf16x8v a0 = *(const bf16x8v*)(Ka + (kr + li)*1024 + h*64 + lg*8);
        bf16x8v a1 = *(const bf16x8v*)(Ka + (kr + li)*1024 + h*64 + 32 + lg*8);
        s16x4 va[4];
        #pragma unroll
        for (int et = 0; et < 4; et++)
            va[et] = *(const s16x4*)(Vt + (long)(h*64 + et*16 + li)*32768 + kr + lg*4);

        f32x4 s[4];
        #pragma unroll
        for (int qt = 0; qt < 4; qt++) {
            f32x4 c = {};
            c = __builtin_amdgcn_mfma_f32_16x16x32_bf16(a0, qf[qt][0], c, 0, 0, 0);
            c = __builtin_amdgcn_mfma_f32_16x16x32_bf16(a1, qf[qt][1], c, 0, 0, 0);
            s[qt] = c;
        }
        float p[4][4];
        #pragma unroll
        for (int qt = 0; qt < 4; qt++)
            #pragma unroll
            for (int j = 0; j < 4; j++)
                p[qt][j] = __builtin_amdgcn_exp2f(s[qt][j]);
        float rz[4];
        #pragma unroll
        for (int j = 0; j < 4; j++) {
            float z = p[0][j] + p[1][j] + p[2][j] + p[3][j];
            z += __shfl_xor(z, 1); z += __shfl_xor(z, 2);
            z += __shfl_xor(z, 4); z += __shfl_xor(z, 8);
            rz[j] = __builtin_amdgcn_rcpf(z);
        }
        s16x4 wf[4];
        #pragma unroll
        for (int qt = 0; qt < 4; qt++) {
            bf16x4v w;
            #pragma unroll
            for (int j = 0; j < 4; j++) w[j] = (__bf16)(p[qt][j] * rz[j]);
            wf[qt] = __builtin_bit_cast(s16x4, w);
        }
        #pragma unroll
        for (int et = 0; et < 4; et++)
            #pragma unroll
            for (int qt = 0; qt < 4; qt++)
                acc[et][qt] = __builtin_amdgcn_mfma_f32_16x16x16bf16_1k(
                    va[et], wf[qt], acc[et][qt], 0, 0, 0);
    }

    __shared__ float Osum[64*64];
    for (int w = 0; w < 4; w++) {
        if (wave == w) {
            #pragma unroll
            for (int et = 0; et < 4; et++)
                #pragma unroll
                for (int qt = 0; qt < 4; qt++)
                    #pragma unroll
                    for (int j = 0; j < 4; j++) {
                        int e = et*16 + lg*4 + j, q = qt*16 + li;
                        if (w == 0) Osum[e*64 + q]  = acc[et][qt][j];
                        else        Osum[e*64 + q] += acc[et][qt][j];
                    }
        }
        __syncthreads();
    }
    const int q = tid & 63, e0 = (tid >> 6) * 16;
    u16x8 o0, o1;
    #pragma unroll
    for (int i = 0; i < 8; i++) {
        o0[i] = f2b(0.5f * Osum[(e0 + i    )*64 + q]);
        o1[i] = f2b(0.5f * Osum[(e0 + 8 + i)*64 + q]);
    }
    u16* dst = Om + (long)(u*64 + q)*1024 + h*64 + e0;
    *(u16x8*)dst       = o0;
    *(u16x8*)(dst + 8) = o1;
}

// ---------------------------------------------------------------------------
// merged f32->bf16 converts: weights (Wq scaled) + optionally nb and x.
// ---------------------------------------------------------------------------
__global__ __launch_bounds__(256)
void convert_all(const float* __restrict__ Wq, const float* __restrict__ Wk,
                 const float* __restrict__ Wv, const float* __restrict__ Wo,
                 const float* __restrict__ nb, const float* __restrict__ x,
                 u16* __restrict__ wW, u16* __restrict__ Anb,
                 u16* __restrict__ xb, int doA)
{
    const int NW = 524288, NN = 4194304, NX = 262144;
    const int tot = doA ? (NW + NN + NX) : NW;
    const int stride = gridDim.x*256;
    for (int i = blockIdx.x*256 + threadIdx.x; i < tot; i += stride) {
        const float* s; u16* d; float sc = 1.0f;
        if (i < NW) {
            int w = i >> 17;
            long off = (long)(i & 131071) * 8;
            s = (w == 0) ? Wq : (w == 1) ? Wk : (w == 2) ? Wv : Wo;
            s += off;
            d = wW + (long)w*1048576 + off;
            if (w == 0) sc = SCALE_LOG2E;
        } else if (i < NW + NN) {
            long off = (long)(i - NW) * 8;
            s = nb + off; d = Anb + off;
        } else {
            long off = (long)(i - NW - NN) * 8;
            s = x + off; d = xb + off;
        }
        float4 f0 = ((const float4*)s)[0], f1 = ((const float4*)s)[1];
        u16x8 o = { f2b(f0.x*sc), f2b(f0.y*sc), f2b(f0.z*sc), f2b(f0.w*sc),
                    f2b(f1.x*sc), f2b(f1.y*sc), f2b(f1.z*sc), f2b(f1.w*sc) };
        *(u16x8*)d = o;
    }
}

// ---------------------------------------------------------------------------
// tail: blocks 0..255 = last-token row sums (Q=1 softmax => w==1);
//       blocks 256..318 = copy out[0:63] = x[0:63].
// ---------------------------------------------------------------------------
__global__ __launch_bounds__(256)
void tail_kernel(const u16* __restrict__ Vt, u16* __restrict__ Om,
                 const float* __restrict__ x, float* __restrict__ out)
{
    if (blockIdx.x < 256) {
        const int row  = blockIdx.x*4 + (threadIdx.x >> 6);   // 0..1023
        const int lane = threadIdx.x & 63;
        const u16* p = Vt + (long)row*32768 + 31*1024 + lane*16;
        float s = 0.f;
        #pragma unroll
        for (int hf = 0; hf < 2; hf++) {
            bf16x8v v = *(const bf16x8v*)(p + hf*8);
            #pragma unroll
            for (int i = 0; i < 8; i++) s += (float)v[i];
        }
        #pragma unroll
        for (int m = 1; m < 64; m <<= 1) s += __shfl_xor(s, m);
        if (lane == 0) Om[(long)1984*1024 + row] = f2b(0.5f * s);
    } else {
        int i = (blockIdx.x - 256)*256 + threadIdx.x;   // 63*256 float4s
        ((float4*)out)[i] = ((const float4*)x)[i];
    }
}

// ---------------------------------------------------------------------------
extern "C" void kernel_launch(void* const* d_in, const int* in_sizes, int n_in,
                              void* d_out, int out_size, void* d_ws, size_t ws_size,
                              hipStream_t stream)
{
    const float* x  = (const float*)d_in[0];
    const float* nb = (const float*)d_in[1];
    const float* Wq = (const float*)d_in[2];
    const float* Wk = (const float*)d_in[3];
    const float* Wv = (const float*)d_in[4];
    const float* Wo = (const float*)d_in[5];
    float* out = (float*)d_out;
    char*  ws  = (char*)d_ws;

    // ws layout:
    //  [0,8MB)     : bf16 weights Wq(scaled),Wk,Wv,Wo (Wk:Wv contiguous = fused B)
    //  [8,12MB)    : Qa  2048x1024 bf16
    //  [12,16MB)   : Om  2048x1024 bf16 (rows 0..1984 used)
    //  [16,80MB)   : Ka  32768x1024 bf16
    //  [80,144MB)  : Vt  1024x32768 bf16
    //  [144,208MB) : Anb 32768x1024 bf16   (fast path only)
    //  [208,212MB) : xb  2048x1024 bf16    (fast path only)
    if (ws_size < (size_t)144*1024*1024) return;
    const bool big = ws_size >= (size_t)212*1024*1024;
    u16* wW  = (u16*)ws;
    u16* Qa  = (u16*)(ws + (size_t) 8*1024*1024);
    u16* Om  = (u16*)(ws + (size_t)12*1024*1024);
    u16* Ka  = (u16*)(ws + (size_t)16*1024*1024);
    u16* Vt  = (u16*)(ws + (size_t)80*1024*1024);
    u16* Anb = (u16*)(ws + (size_t)144*1024*1024);
    u16* xb  = (u16*)(ws + (size_t)208*1024*1024);
    u16* wWq = wW, *wWk = wW + 1048576, *wWo = wW + 3*1048576;

    convert_all<<<dim3(4096), dim3(256), 0, stream>>>(
        Wq, Wk, Wv, Wo, nb, x, wW, Anb, xb, big ? 1 : 0);

    if (big) {
        // merged KV (1024 blocks) + Q (32 blocks) projection dispatch
        gemm256<<<dim3(1056), dim3(512), 0, stream>>>(
            Anb, wWk, Ka, Vt, xb, wWq, Qa, 1024, 8);
    } else {
        gemm128<true, 0><<<dim3(128), dim3(256), 0, stream>>>(
            x, 1024, wWq, 1024, Qa, nullptr, 2048, 1024, 0, 8);
        gemm128<true, 3><<<dim3(4096), dim3(256), 0, stream>>>(
            nb, 1024, wWk, 1024, Ka, Vt, 32768, 1024, 0, 16);
    }

    attn_kernel<<<dim3(31, 16), dim3(256), 0, stream>>>(Qa, Ka, Vt, Om);
    tail_kernel<<<dim3(319), dim3(256), 0, stream>>>(Vt, Om, x, out);

    gemm128<false, 2><<<dim3(128), dim3(256), 0, stream>>>(
        Om, 1024, wWo, 1024, out, nullptr, 1985, 1024, 63, 8);
}

// Round 18
// 244.132 us; speedup vs baseline: 1.1375x; 1.0104x over previous
//
#include <hip/hip_runtime.h>
#include <hip/hip_bf16.h>

// ChunkedCrossAttention (RETRO-style), MI355X gfx950.
// N=2048 M=64 K=2 R=512 D=1024 H=16 DH=64 LCH=32
//
// Round 18: r17 + tail work (last-token row sums + head copy) folded into
// the attention dispatch as the u==31 block row (grid 32x16). One fewer
// launch; tail overlaps attention instead of serializing after it.

using u16 = unsigned short;
using u32 = unsigned int;

typedef float  f32x4   __attribute__((ext_vector_type(4)));
typedef __bf16 bf16x8v __attribute__((ext_vector_type(8)));
typedef __bf16 bf16x4v __attribute__((ext_vector_type(4)));
typedef short  s16x4   __attribute__((ext_vector_type(4)));
typedef u16    u16x8   __attribute__((ext_vector_type(8)));
typedef u16    u16x4v  __attribute__((ext_vector_type(4)));

#define SCALE_LOG2E (1.4426950408889634f / 32.0f)

__device__ __forceinline__ u16 f2b(float f){ return __builtin_bit_cast(u16, (__bf16)f); }
// XOR swizzle on 16B slots within 128B LDS rows
__device__ __forceinline__ int swz(int row, int cb){ return row*128 + (cb ^ ((row & 7) << 4)); }

// async global->LDS, 16B per lane, wave-uniform LDS base (guide §5 / m97)
__device__ __forceinline__ void gl_lds16(const void* g, void* l) {
    __builtin_amdgcn_global_load_lds(
        (const __attribute__((address_space(1))) unsigned int*)(unsigned long long)g,
        (__attribute__((address_space(3))) unsigned int*)(unsigned int)(unsigned long long)l,
        16, 0, 0);
}

// ===========================================================================
// 256x256 GEMM, r10 K-loop (best measured). Dual-problem dispatch:
//   lin2 <  nKV : KV blocks  — A=Ap(Anb), B=Bp(wWk:wWv), epilogue Ka / Vt^T
//   lin2 >= nKV : Q  blocks  — A=Aq(xb),  B=Bq(wWq),     epilogue Qa row-major
// All dims multiples of 256 (KV: 32768x2048; Q: 2048x1024), Kc=1024 both.
// 512 threads = 8 waves (2M x 4N), per-wave 128x64 output, BK=64, NT=16.
// LDS 128KB: A dbuf[2] x half[2] x 16KB at [0,64K); B same at [64K,128K).
// Per tile: 2 barriers, issue-ahead ds_reads (compiler-counted lgkm),
// register-reused operands, precomputed per-lane stage pointers, counted
// vmcnt(2) at MID/END (r10 schedule, verified).
// ===========================================================================
__global__ __launch_bounds__(512, 2)
void gemm256(const u16* __restrict__ Ap, const u16* __restrict__ Bp,
             u16* __restrict__ Ka, u16* __restrict__ Vt,
             const u16* __restrict__ Aq, const u16* __restrict__ Bq,
             u16* __restrict__ Qa,
             int nKV, int nNt)
{
    __shared__ char Ls[131072];
    char* const Abase = Ls;
    char* const Bbase = Ls + 65536;

    const int tid  = threadIdx.x;
    const int lane = tid & 63, wave = tid >> 6;
    const int li = lane & 15, lg = lane >> 4;
    const int wr = wave >> 2, wc = wave & 3;

    const int nwg  = gridDim.x;
    const int lin  = blockIdx.x;
    const int lin2 = (lin & 7) * (nwg >> 3) + (lin >> 3);   // XCD chunk swizzle

    const bool isQ = (lin2 >= nKV);
    long bm, bn;
    if (isQ) { const int idx = lin2 - nKV; bm = (long)(idx >> 2) * 256; bn = (long)(idx & 3) * 256; }
    else     {                              bm = (long)(lin2 / nNt) * 256; bn = (long)(lin2 % nNt) * 256; }
    const u16* const Ag = isQ ? Aq : Ap;    // lda = ldb = 1024 for all
    const u16* const Bg = isQ ? Bq : Bp;

    const int srow = tid >> 3;                         // 0..63
    const int scol = ((tid & 7) ^ (srow & 7)) << 3;    // pre-swizzled col (elems)

    const u16* const pA0 = Ag + (bm + srow)*1024L + scol;
    const u16* const pA1 = Ag + (bm + 128 + srow)*1024L + scol;
    const u16* const pB0 = Bg + (bn + srow)*1024L + scol;
    const u16* const pB1 = Bg + (bn + 128 + srow)*1024L + scol;
    const long l64 = 64*1024L;

    auto stA = [&](int t, int hh) {
        char* d = Abase + (t & 1)*32768 + hh*16384 + wave*1024;
        const u16* p = (hh ? pA1 : pA0) + (long)t*64;
        gl_lds16(p, d);
        gl_lds16(p + l64, d + 8192);
    };
    auto stB = [&](int t, int hh) {
        char* d = Bbase + (t & 1)*32768 + hh*16384 + wave*1024;
        const u16* p = (hh ? pB1 : pB0) + (long)t*64;
        gl_lds16(p, d);
        gl_lds16(p + l64, d + 8192);
    };

    const int NT = 16;   // Kc = 1024 for both problems

    // prologue: tile0 (8 loads) + B0(1) (2) = 10; vmcnt(2) -> tile0 landed
    stB(0, 0); stB(0, 1); stA(0, 0); stA(0, 1); stB(1, 0);
    asm volatile("s_waitcnt vmcnt(2)" ::: "memory");
    asm volatile("s_barrier" ::: "memory");

    const int swx = (li & 7) << 4;
    const int cb0 = (lg*16) ^ swx;          // k-step 0 column bytes (swizzled)
    const int cb1 = (64 + lg*16) ^ swx;     // k-step 1
    const int brb = (wc & 1)*64 + li;       // B row within wc>>1 half

    f32x4 acc[8][4] = {};
    bf16x8v av[4], aw[4], bv[4];

#define MFMA16(MH, AA, BB)                                                      \
    __builtin_amdgcn_s_setprio(1);                                              \
    _Pragma("unroll") for (int mt = 0; mt < 4; mt++)                            \
        _Pragma("unroll") for (int nt = 0; nt < 4; nt++)                        \
            acc[(MH)*4 + mt][nt] = __builtin_amdgcn_mfma_f32_16x16x32_bf16(     \
                (AA)[mt], (BB)[nt], acc[(MH)*4 + mt][nt], 0, 0, 0);             \
    __builtin_amdgcn_s_setprio(0);
#define RDA(DST, OFS, CB)                                                       \
    _Pragma("unroll") for (int i = 0; i < 4; i++)                               \
        (DST)[i] = *(const bf16x8v*)(At + (li + (OFS) + i*16)*128 + (CB));
#define RDB(DST, CB)                                                            \
    _Pragma("unroll") for (int i = 0; i < 4; i++)                               \
        (DST)[i] = *(const bf16x8v*)(Bt + (brb + i*16)*128 + (CB));

    for (int t = 0; t < NT; ++t) {
        char* At = Abase + (t & 1)*32768 + wr*16384;
        char* Bt = Bbase + (t & 1)*32768 + (wc >> 1)*16384;
        const bool s1 = (t + 1 < NT), s2 = (t + 2 < NT);

        RDA(av, 0, cb0); RDB(bv, cb0);
        if (s1) { stB(t + 1, 1); stA(t + 1, 0); }
        RDA(aw, 64, cb0);
        __builtin_amdgcn_sched_barrier(0);
        MFMA16(0, av, bv);
        if (s1) stA(t + 1, 1);
        RDA(av, 0, cb1);
        __builtin_amdgcn_sched_barrier(0);
        MFMA16(1, aw, bv);
        RDB(bv, cb1); RDA(aw, 64, cb1);
        __builtin_amdgcn_sched_barrier(0);
        MFMA16(0, av, bv);
        asm volatile("s_barrier" ::: "memory");   // MID: all waves' b@k1 reads done
        if (s2) stB(t + 2, 0);
        MFMA16(1, aw, bv);
        if      (s2) { asm volatile("s_waitcnt vmcnt(2)" ::: "memory"); }
        else if (s1) { asm volatile("s_waitcnt vmcnt(0)" ::: "memory"); }
        asm volatile("s_barrier" ::: "memory");   // END: publish t+1 stages
    }
#undef MFMA16
#undef RDA
#undef RDB

    if (!isQ && bn >= 1024) {
        // --- V-block epilogue: LDS transpose -> coalesced Vt stores ---
        #pragma unroll
        for (int ai = 0; ai < 8; ai++) {
            const int m0 = wr*128 + (ai >> 2)*64 + (ai & 3)*16 + lg*4;   // 4-aligned
            #pragma unroll
            for (int nt = 0; nt < 4; nt++) {
                const int n = wc*64 + nt*16 + li;
                f32x4 c = acc[ai][nt];
                bf16x4v w;
                #pragma unroll
                for (int j = 0; j < 4; j++) w[j] = (__bf16)c[j];
                *(bf16x4v*)(Ls + n*512 + ((m0*2) ^ ((n & 31) << 4))) = w;
            }
        }
        __syncthreads();
        const int n    = tid >> 1;              // Vt-local row 0..255
        const int half = (tid & 1) * 128;       // m half
        u16* dst = Vt + (bn - 1024 + n)*32768L + bm + half;
        #pragma unroll
        for (int i = 0; i < 16; i++) {
            const int mb = (half + i*8) * 2;    // byte offset, 16B aligned
            uint4 v = *(const uint4*)(Ls + n*512 + (mb ^ ((n & 31) << 4)));
            *(uint4*)(dst + i*8) = v;
        }
    } else {
        // --- row-major 2B stores: Ka (KV, bn<1024) or Qa (Q blocks) ---
        u16* Co = isQ ? Qa : Ka;
        #pragma unroll
        for (int ai = 0; ai < 8; ai++) {
            #pragma unroll
            for (int nt = 0; nt < 4; nt++) {
                f32x4 c = acc[ai][nt];
                const long row0 = bm + wr*128 + (ai >> 2)*64 + (ai & 3)*16 + lg*4;
                const long col  = bn + wc*64 + nt*16 + li;
                #pragma unroll
                for (int j = 0; j < 4; j++)
                    Co[(row0 + j)*1024 + col] = f2b(c[j]);
            }
        }
    }
}

// ---------------------------------------------------------------------------
// 128x128x64-step GEMM (Wo projection + small-ws fallback), unchanged.
// ---------------------------------------------------------------------------
template<bool AF32, int OM>
__global__ __launch_bounds__(256)
void gemm128(const void* __restrict__ Ap, int lda,
             const u16* __restrict__ Bp, int ldb,
             void* __restrict__ Cp, void* __restrict__ Cp2,
             int M, int Kc, int row_off, int nNt)
{
    __shared__ char As[128*128];
    __shared__ char Bs[128*128];
    const int tid  = threadIdx.x;
    const int lane = tid & 63, wave = tid >> 6;
    const int li = lane & 15, lg = lane >> 4;
    const int wr = wave >> 1, wc = wave & 1;

    const int nwg  = gridDim.x;
    const int lin  = blockIdx.x;
    const int lin2 = (lin & 7) * (nwg >> 3) + (lin >> 3);
    const long bm = (long)(lin2 / nNt) * 128;
    const long bn = (long)(lin2 % nNt) * 128;

    const int grow = wave*32 + (lane >> 3);
    const int gcol = ((lane & 7) ^ (lane >> 3)) << 3;
    const int sr = tid >> 1, sc = (tid & 1) * 32;
    long arow_f = bm + sr; if (arow_f >= M) arow_f = M - 1;
    long arow_g[4];
    #pragma unroll
    for (int j = 0; j < 4; j++) {
        long r = bm + grow + j*8;
        arow_g[j] = (r < M) ? r : (M - 1);
    }

    f32x4 acc[4][4] = {};

    for (int k0 = 0; k0 < Kc; k0 += 64) {
        float4 a4[8];
        if (AF32) {
            const float4* ap = (const float4*)((const float*)Ap + arow_f*lda + k0 + sc);
            #pragma unroll
            for (int i = 0; i < 8; i++) a4[i] = ap[i];
        }
        __syncthreads();
        if (!AF32) {
            #pragma unroll
            for (int j = 0; j < 4; j++)
                gl_lds16((const u16*)Ap + arow_g[j]*(long)lda + k0 + gcol,
                         As + (wave*4 + j)*1024);
        }
        #pragma unroll
        for (int j = 0; j < 4; j++)
            gl_lds16(Bp + (bn + grow + j*8)*(long)ldb + k0 + gcol,
                     Bs + (wave*4 + j)*1024);
        if (AF32) {
            #pragma unroll
            for (int i = 0; i < 4; i++) {
                float4 f0 = a4[2*i], f1 = a4[2*i+1];
                bf16x8v w;
                w[0]=(__bf16)f0.x; w[1]=(__bf16)f0.y; w[2]=(__bf16)f0.z; w[3]=(__bf16)f0.w;
                w[4]=(__bf16)f1.x; w[5]=(__bf16)f1.y; w[6]=(__bf16)f1.z; w[7]=(__bf16)f1.w;
                *(bf16x8v*)(As + swz(sr, sc*2 + i*16)) = w;
            }
        }
        __syncthreads();
        #pragma unroll
        for (int es = 0; es < 2; es++) {
            bf16x8v af[4], bfv[4];
            #pragma unroll
            for (int mt = 0; mt < 4; mt++)
                af[mt] = *(const bf16x8v*)(As + swz(wr*64 + mt*16 + li, es*64 + lg*16));
            #pragma unroll
            for (int nt = 0; nt < 4; nt++)
                bfv[nt] = *(const bf16x8v*)(Bs + swz(wc*64 + nt*16 + li, es*64 + lg*16));
            #pragma unroll
            for (int mt = 0; mt < 4; mt++)
                #pragma unroll
                for (int nt = 0; nt < 4; nt++)
                    acc[mt][nt] = __builtin_amdgcn_mfma_f32_16x16x32_bf16(
                        af[mt], bfv[nt], acc[mt][nt], 0, 0, 0);
        }
    }

    #pragma unroll
    for (int mt = 0; mt < 4; mt++) {
        #pragma unroll
        for (int nt = 0; nt < 4; nt++) {
            f32x4 c = acc[mt][nt];
            const long row0 = bm + wr*64 + mt*16 + lg*4;
            const long col  = bn + wc*64 + nt*16 + li;
            if (OM == 0) {
                u16* C = (u16*)Cp;
                #pragma unroll
                for (int j = 0; j < 4; j++) {
                    long rg = row0 + j;
                    if (rg < M) C[rg*1024 + col] = f2b(c[j]);
                }
            } else if (OM == 2) {
                float* C = (float*)Cp;
                #pragma unroll
                for (int j = 0; j < 4; j++) {
                    long rg = row0 + j;
                    if (rg < M) C[(row_off + rg)*1024 + col] = c[j];
                }
            } else {
                if (col < 1024) {
                    u16* Ka = (u16*)Cp;
                    #pragma unroll
                    for (int j = 0; j < 4; j++) Ka[(row0 + j)*1024 + col] = f2b(c[j]);
                } else {
                    u16* Vt = (u16*)Cp2;
                    bf16x4v w;
                    #pragma unroll
                    for (int j = 0; j < 4; j++) w[j] = (__bf16)c[j];
                    *(bf16x4v*)(Vt + (col - 1024)*32768L + row0) = w;
                }
            }
        }
    }
}

// ---------------------------------------------------------------------------
// Fused attention: grid (32, 16). u<31: attention for chunk u, head h.
// u==31: tail row-block h — 64 last-token row sums + 1/16 of head copy.
// ---------------------------------------------------------------------------
__global__ __launch_bounds__(256)
void attn_kernel(const u16* __restrict__ Qa, const u16* __restrict__ Ka,
                 const u16* __restrict__ Vt, u16* __restrict__ Om,
                 const float* __restrict__ x, float* __restrict__ out)
{
    const int u = blockIdx.x, h = blockIdx.y;
    const int tid = threadIdx.x;
    const int lane = tid & 63, wave = tid >> 6;
    const int li = lane & 15, lg = lane >> 4;

    if (u == 31) {
        // --- last-token: Om[1984][l] = 0.5 * sum_{k,r} V[l][chunk31] ---
        // rows h*64 .. h*64+63, 4 waves x 16 iterations, 64-lane reduce each
        #pragma unroll 4
        for (int it = 0; it < 16; ++it) {
            const int row = h*64 + it*4 + wave;          // 0..1023
            const u16* p = Vt + (long)row*32768 + 31*1024 + lane*16;
            float s = 0.f;
            #pragma unroll
            for (int hf = 0; hf < 2; hf++) {
                bf16x8v v = *(const bf16x8v*)(p + hf*8);
                #pragma unroll
                for (int i = 0; i < 8; i++) s += (float)v[i];
            }
            #pragma unroll
            for (int m = 1; m < 64; m <<= 1) s += __shfl_xor(s, m);
            if (lane == 0) Om[(long)1984*1024 + row] = f2b(0.5f * s);
        }
        // --- head copy: out[0:63] = x[0:63]  (16128 float4s over 16 blocks) ---
        for (int i = h*1008 + tid; i < (h + 1)*1008; i += 256)
            ((float4*)out)[i] = ((const float4*)x)[i];
        return;
    }

    bf16x8v qf[4][2];
    #pragma unroll
    for (int qt = 0; qt < 4; qt++)
        #pragma unroll
        for (int es = 0; es < 2; es++)
            qf[qt][es] = *(const bf16x8v*)(Qa + (long)(63 + u*64 + qt*16 + li)*1024
                                              + h*64 + es*32 + lg*8);

    f32x4 acc[4][4] = {};

    for (int it = wave; it < 64; it += 4) {
        const int k = it >> 5, rsub = it & 31;
        const long kr = (long)u*1024 + k*512 + rsub*16;

        bf16x8v a0 = *(const bf16x8v*)(Ka + (kr + li)*1024 + h*64 + lg*8);
        bf16x8v a1 = *(const bf16x8v*)(Ka + (kr + li)*1024 + h*64 + 32 + lg*8);
        s16x4 va[4];
        #pragma unroll
        for (int et = 0; et < 4; et++)
            va[et] = *(const s16x4*)(Vt + (long)(h*64 + et*16 + li)*32768 + kr + lg*4);

        f32x4 s[4];
        #pragma unroll
        for (int qt = 0; qt < 4; qt++) {
            f32x4 c = {};
            c = __builtin_amdgcn_mfma_f32_16x16x32_bf16(a0, qf[qt][0], c, 0, 0, 0);
            c = __builtin_amdgcn_mfma_f32_16x16x32_bf16(a1, qf[qt][1], c, 0, 0, 0);
            s[qt] = c;
        }
        float p[4][4];
        #pragma unroll
        for (int qt = 0; qt < 4; qt++)
            #pragma unroll
            for (int j = 0; j < 4; j++)
                p[qt][j] = __builtin_amdgcn_exp2f(s[qt][j]);
        float rz[4];
        #pragma unroll
        for (int j = 0; j < 4; j++) {
            float z = p[0][j] + p[1][j] + p[2][j] + p[3][j];
            z += __shfl_xor(z, 1); z += __shfl_xor(z, 2);
            z += __shfl_xor(z, 4); z += __shfl_xor(z, 8);
            rz[j] = __builtin_amdgcn_rcpf(z);
        }
        s16x4 wf[4];
        #pragma unroll
        for (int qt = 0; qt < 4; qt++) {
            bf16x4v w;
            #pragma unroll
            for (int j = 0; j < 4; j++) w[j] = (__bf16)(p[qt][j] * rz[j]);
            wf[qt] = __builtin_bit_cast(s16x4, w);
        }
        #pragma unroll
        for (int et = 0; et < 4; et++)
            #pragma unroll
            for (int qt = 0; qt < 4; qt++)
                acc[et][qt] = __builtin_amdgcn_mfma_f32_16x16x16bf16_1k(
                    va[et], wf[qt], acc[et][qt], 0, 0, 0);
    }

    __shared__ float Osum[64*64];
    for (int w = 0; w < 4; w++) {
        if (wave == w) {
            #pragma unroll
            for (int et = 0; et < 4; et++)
                #pragma unroll
                for (int qt = 0; qt < 4; qt++)
                    #pragma unroll
                    for (int j = 0; j < 4; j++) {
                        int e = et*16 + lg*4 + j, q = qt*16 + li;
                        if (w == 0) Osum[e*64 + q]  = acc[et][qt][j];
                        else        Osum[e*64 + q] += acc[et][qt][j];
                    }
        }
        __syncthreads();
    }
    const int q = tid & 63, e0 = (tid >> 6) * 16;
    u16x8 o0, o1;
    #pragma unroll
    for (int i = 0; i < 8; i++) {
        o0[i] = f2b(0.5f * Osum[(e0 + i    )*64 + q]);
        o1[i] = f2b(0.5f * Osum[(e0 + 8 + i)*64 + q]);
    }
    u16* dst = Om + (long)(u*64 + q)*1024 + h*64 + e0;
    *(u16x8*)dst       = o0;
    *(u16x8*)(dst + 8) = o1;
}

// ---------------------------------------------------------------------------
// merged f32->bf16 converts: weights (Wq scaled) + optionally nb and x.
// ---------------------------------------------------------------------------
__global__ __launch_bounds__(256)
void convert_all(const float* __restrict__ Wq, const float* __restrict__ Wk,
                 const float* __restrict__ Wv, const float* __restrict__ Wo,
                 const float* __restrict__ nb, const float* __restrict__ x,
                 u16* __restrict__ wW, u16* __restrict__ Anb,
                 u16* __restrict__ xb, int doA)
{
    const int NW = 524288, NN = 4194304, NX = 262144;
    const int tot = doA ? (NW + NN + NX) : NW;
    const int stride = gridDim.x*256;
    for (int i = blockIdx.x*256 + threadIdx.x; i < tot; i += stride) {
        const float* s; u16* d; float sc = 1.0f;
        if (i < NW) {
            int w = i >> 17;
            long off = (long)(i & 131071) * 8;
            s = (w == 0) ? Wq : (w == 1) ? Wk : (w == 2) ? Wv : Wo;
            s += off;
            d = wW + (long)w*1048576 + off;
            if (w == 0) sc = SCALE_LOG2E;
        } else if (i < NW + NN) {
            long off = (long)(i - NW) * 8;
            s = nb + off; d = Anb + off;
        } else {
            long off = (long)(i - NW - NN) * 8;
            s = x + off; d = xb + off;
        }
        float4 f0 = ((const float4*)s)[0], f1 = ((const float4*)s)[1];
        u16x8 o = { f2b(f0.x*sc), f2b(f0.y*sc), f2b(f0.z*sc), f2b(f0.w*sc),
                    f2b(f1.x*sc), f2b(f1.y*sc), f2b(f1.z*sc), f2b(f1.w*sc) };
        *(u16x8*)d = o;
    }
}

// ---------------------------------------------------------------------------
// tail for the small-ws fallback path only (fallback attn stays (31,16)).
// ---------------------------------------------------------------------------
__global__ __launch_bounds__(256)
void tail_kernel(const u16* __restrict__ Vt, u16* __restrict__ Om,
                 const float* __restrict__ x, float* __restrict__ out)
{
    if (blockIdx.x < 256) {
        const int row  = blockIdx.x*4 + (threadIdx.x >> 6);   // 0..1023
        const int lane = threadIdx.x & 63;
        const u16* p = Vt + (long)row*32768 + 31*1024 + lane*16;
        float s = 0.f;
        #pragma unroll
        for (int hf = 0; hf < 2; hf++) {
            bf16x8v v = *(const bf16x8v*)(p + hf*8);
            #pragma unroll
            for (int i = 0; i < 8; i++) s += (float)v[i];
        }
        #pragma unroll
        for (int m = 1; m < 64; m <<= 1) s += __shfl_xor(s, m);
        if (lane == 0) Om[(long)1984*1024 + row] = f2b(0.5f * s);
    } else {
        int i = (blockIdx.x - 256)*256 + threadIdx.x;   // 63*256 float4s
        ((float4*)out)[i] = ((const float4*)x)[i];
    }
}

// ---------------------------------------------------------------------------
extern "C" void kernel_launch(void* const* d_in, const int* in_sizes, int n_in,
                              void* d_out, int out_size, void* d_ws, size_t ws_size,
                              hipStream_t stream)
{
    const float* x  = (const float*)d_in[0];
    const float* nb = (const float*)d_in[1];
    const float* Wq = (const float*)d_in[2];
    const float* Wk = (const float*)d_in[3];
    const float* Wv = (const float*)d_in[4];
    const float* Wo = (const float*)d_in[5];
    float* out = (float*)d_out;
    char*  ws  = (char*)d_ws;

    // ws layout:
    //  [0,8MB)     : bf16 weights Wq(scaled),Wk,Wv,Wo (Wk:Wv contiguous = fused B)
    //  [8,12MB)    : Qa  2048x1024 bf16
    //  [12,16MB)   : Om  2048x1024 bf16 (rows 0..1984 used)
    //  [16,80MB)   : Ka  32768x1024 bf16
    //  [80,144MB)  : Vt  1024x32768 bf16
    //  [144,208MB) : Anb 32768x1024 bf16   (fast path only)
    //  [208,212MB) : xb  2048x1024 bf16    (fast path only)
    if (ws_size < (size_t)144*1024*1024) return;
    const bool big = ws_size >= (size_t)212*1024*1024;
    u16* wW  = (u16*)ws;
    u16* Qa  = (u16*)(ws + (size_t) 8*1024*1024);
    u16* Om  = (u16*)(ws + (size_t)12*1024*1024);
    u16* Ka  = (u16*)(ws + (size_t)16*1024*1024);
    u16* Vt  = (u16*)(ws + (size_t)80*1024*1024);
    u16* Anb = (u16*)(ws + (size_t)144*1024*1024);
    u16* xb  = (u16*)(ws + (size_t)208*1024*1024);
    u16* wWq = wW, *wWk = wW + 1048576, *wWo = wW + 3*1048576;

    convert_all<<<dim3(4096), dim3(256), 0, stream>>>(
        Wq, Wk, Wv, Wo, nb, x, wW, Anb, xb, big ? 1 : 0);

    if (big) {
        // merged KV (1024 blocks) + Q (32 blocks) projection dispatch
        gemm256<<<dim3(1056), dim3(512), 0, stream>>>(
            Anb, wWk, Ka, Vt, xb, wWq, Qa, 1024, 8);
        // attention + fused tail (u==31 row)
        attn_kernel<<<dim3(32, 16), dim3(256), 0, stream>>>(Qa, Ka, Vt, Om, x, out);
    } else {
        gemm128<true, 0><<<dim3(128), dim3(256), 0, stream>>>(
            x, 1024, wWq, 1024, Qa, nullptr, 2048, 1024, 0, 8);
        gemm128<true, 3><<<dim3(4096), dim3(256), 0, stream>>>(
            nb, 1024, wWk, 1024, Ka, Vt, 32768, 1024, 0, 16);
        attn_kernel<<<dim3(32, 16), dim3(256), 0, stream>>>(Qa, Ka, Vt, Om, x, out);
    }

    gemm128<false, 2><<<dim3(128), dim3(256), 0, stream>>>(
        Om, 1024, wWo, 1024, out, nullptr, 1985, 1024, 63, 8);
}

// Round 19
// 241.312 us; speedup vs baseline: 1.1508x; 1.0117x over previous
//
#include <hip/hip_runtime.h>
#include <hip/hip_bf16.h>

// ChunkedCrossAttention (RETRO-style), MI355X gfx950.
// N=2048 M=64 K=2 R=512 D=1024 H=16 DH=64 LCH=32
//
// Round 19: r18 + Wo projection split-K x2 (single 256-block dispatch, f32
// partials Pa/Pb in dead Anb space, deterministic combine). Full machine on
// the Wo GEMM instead of half.

using u16 = unsigned short;
using u32 = unsigned int;

typedef float  f32x4   __attribute__((ext_vector_type(4)));
typedef __bf16 bf16x8v __attribute__((ext_vector_type(8)));
typedef __bf16 bf16x4v __attribute__((ext_vector_type(4)));
typedef short  s16x4   __attribute__((ext_vector_type(4)));
typedef u16    u16x8   __attribute__((ext_vector_type(8)));
typedef u16    u16x4v  __attribute__((ext_vector_type(4)));

#define SCALE_LOG2E (1.4426950408889634f / 32.0f)

__device__ __forceinline__ u16 f2b(float f){ return __builtin_bit_cast(u16, (__bf16)f); }
// XOR swizzle on 16B slots within 128B LDS rows
__device__ __forceinline__ int swz(int row, int cb){ return row*128 + (cb ^ ((row & 7) << 4)); }

// async global->LDS, 16B per lane, wave-uniform LDS base (guide §5 / m97)
__device__ __forceinline__ void gl_lds16(const void* g, void* l) {
    __builtin_amdgcn_global_load_lds(
        (const __attribute__((address_space(1))) unsigned int*)(unsigned long long)g,
        (__attribute__((address_space(3))) unsigned int*)(unsigned int)(unsigned long long)l,
        16, 0, 0);
}

// ===========================================================================
// 256x256 GEMM, r10 K-loop (best measured). Dual-problem dispatch:
//   lin2 <  nKV : KV blocks  — A=Ap(Anb), B=Bp(wWk:wWv), epilogue Ka / Vt^T
//   lin2 >= nKV : Q  blocks  — A=Aq(xb),  B=Bq(wWq),     epilogue Qa row-major
// ===========================================================================
__global__ __launch_bounds__(512, 2)
void gemm256(const u16* __restrict__ Ap, const u16* __restrict__ Bp,
             u16* __restrict__ Ka, u16* __restrict__ Vt,
             const u16* __restrict__ Aq, const u16* __restrict__ Bq,
             u16* __restrict__ Qa,
             int nKV, int nNt)
{
    __shared__ char Ls[131072];
    char* const Abase = Ls;
    char* const Bbase = Ls + 65536;

    const int tid  = threadIdx.x;
    const int lane = tid & 63, wave = tid >> 6;
    const int li = lane & 15, lg = lane >> 4;
    const int wr = wave >> 2, wc = wave & 3;

    const int nwg  = gridDim.x;
    const int lin  = blockIdx.x;
    const int lin2 = (lin & 7) * (nwg >> 3) + (lin >> 3);   // XCD chunk swizzle

    const bool isQ = (lin2 >= nKV);
    long bm, bn;
    if (isQ) { const int idx = lin2 - nKV; bm = (long)(idx >> 2) * 256; bn = (long)(idx & 3) * 256; }
    else     {                              bm = (long)(lin2 / nNt) * 256; bn = (long)(lin2 % nNt) * 256; }
    const u16* const Ag = isQ ? Aq : Ap;    // lda = ldb = 1024 for all
    const u16* const Bg = isQ ? Bq : Bp;

    const int srow = tid >> 3;                         // 0..63
    const int scol = ((tid & 7) ^ (srow & 7)) << 3;    // pre-swizzled col (elems)

    const u16* const pA0 = Ag + (bm + srow)*1024L + scol;
    const u16* const pA1 = Ag + (bm + 128 + srow)*1024L + scol;
    const u16* const pB0 = Bg + (bn + srow)*1024L + scol;
    const u16* const pB1 = Bg + (bn + 128 + srow)*1024L + scol;
    const long l64 = 64*1024L;

    auto stA = [&](int t, int hh) {
        char* d = Abase + (t & 1)*32768 + hh*16384 + wave*1024;
        const u16* p = (hh ? pA1 : pA0) + (long)t*64;
        gl_lds16(p, d);
        gl_lds16(p + l64, d + 8192);
    };
    auto stB = [&](int t, int hh) {
        char* d = Bbase + (t & 1)*32768 + hh*16384 + wave*1024;
        const u16* p = (hh ? pB1 : pB0) + (long)t*64;
        gl_lds16(p, d);
        gl_lds16(p + l64, d + 8192);
    };

    const int NT = 16;   // Kc = 1024 for both problems

    stB(0, 0); stB(0, 1); stA(0, 0); stA(0, 1); stB(1, 0);
    asm volatile("s_waitcnt vmcnt(2)" ::: "memory");
    asm volatile("s_barrier" ::: "memory");

    const int swx = (li & 7) << 4;
    const int cb0 = (lg*16) ^ swx;
    const int cb1 = (64 + lg*16) ^ swx;
    const int brb = (wc & 1)*64 + li;

    f32x4 acc[8][4] = {};
    bf16x8v av[4], aw[4], bv[4];

#define MFMA16(MH, AA, BB)                                                      \
    __builtin_amdgcn_s_setprio(1);                                              \
    _Pragma("unroll") for (int mt = 0; mt < 4; mt++)                            \
        _Pragma("unroll") for (int nt = 0; nt < 4; nt++)                        \
            acc[(MH)*4 + mt][nt] = __builtin_amdgcn_mfma_f32_16x16x32_bf16(     \
                (AA)[mt], (BB)[nt], acc[(MH)*4 + mt][nt], 0, 0, 0);             \
    __builtin_amdgcn_s_setprio(0);
#define RDA(DST, OFS, CB)                                                       \
    _Pragma("unroll") for (int i = 0; i < 4; i++)                               \
        (DST)[i] = *(const bf16x8v*)(At + (li + (OFS) + i*16)*128 + (CB));
#define RDB(DST, CB)                                                            \
    _Pragma("unroll") for (int i = 0; i < 4; i++)                               \
        (DST)[i] = *(const bf16x8v*)(Bt + (brb + i*16)*128 + (CB));

    for (int t = 0; t < NT; ++t) {
        char* At = Abase + (t & 1)*32768 + wr*16384;
        char* Bt = Bbase + (t & 1)*32768 + (wc >> 1)*16384;
        const bool s1 = (t + 1 < NT), s2 = (t + 2 < NT);

        RDA(av, 0, cb0); RDB(bv, cb0);
        if (s1) { stB(t + 1, 1); stA(t + 1, 0); }
        RDA(aw, 64, cb0);
        __builtin_amdgcn_sched_barrier(0);
        MFMA16(0, av, bv);
        if (s1) stA(t + 1, 1);
        RDA(av, 0, cb1);
        __builtin_amdgcn_sched_barrier(0);
        MFMA16(1, aw, bv);
        RDB(bv, cb1); RDA(aw, 64, cb1);
        __builtin_amdgcn_sched_barrier(0);
        MFMA16(0, av, bv);
        asm volatile("s_barrier" ::: "memory");   // MID
        if (s2) stB(t + 2, 0);
        MFMA16(1, aw, bv);
        if      (s2) { asm volatile("s_waitcnt vmcnt(2)" ::: "memory"); }
        else if (s1) { asm volatile("s_waitcnt vmcnt(0)" ::: "memory"); }
        asm volatile("s_barrier" ::: "memory");   // END
    }
#undef MFMA16
#undef RDA
#undef RDB

    if (!isQ && bn >= 1024) {
        // --- V-block epilogue: LDS transpose -> coalesced Vt stores ---
        #pragma unroll
        for (int ai = 0; ai < 8; ai++) {
            const int m0 = wr*128 + (ai >> 2)*64 + (ai & 3)*16 + lg*4;
            #pragma unroll
            for (int nt = 0; nt < 4; nt++) {
                const int n = wc*64 + nt*16 + li;
                f32x4 c = acc[ai][nt];
                bf16x4v w;
                #pragma unroll
                for (int j = 0; j < 4; j++) w[j] = (__bf16)c[j];
                *(bf16x4v*)(Ls + n*512 + ((m0*2) ^ ((n & 31) << 4))) = w;
            }
        }
        __syncthreads();
        const int n    = tid >> 1;
        const int half = (tid & 1) * 128;
        u16* dst = Vt + (bn - 1024 + n)*32768L + bm + half;
        #pragma unroll
        for (int i = 0; i < 16; i++) {
            const int mb = (half + i*8) * 2;
            uint4 v = *(const uint4*)(Ls + n*512 + (mb ^ ((n & 31) << 4)));
            *(uint4*)(dst + i*8) = v;
        }
    } else {
        u16* Co = isQ ? Qa : Ka;
        #pragma unroll
        for (int ai = 0; ai < 8; ai++) {
            #pragma unroll
            for (int nt = 0; nt < 4; nt++) {
                f32x4 c = acc[ai][nt];
                const long row0 = bm + wr*128 + (ai >> 2)*64 + (ai & 3)*16 + lg*4;
                const long col  = bn + wc*64 + nt*16 + li;
                #pragma unroll
                for (int j = 0; j < 4; j++)
                    Co[(row0 + j)*1024 + col] = f2b(c[j]);
            }
        }
    }
}

// ---------------------------------------------------------------------------
// 128x128x64-step GEMM.
// OM=0: bf16 C. OM=2: f32 C with row_off. OM=3: fused KV (fallback).
// OM=5: split-K Wo — blocks [0,128) K-half 0 -> Cp, [128,256) K-half 1 -> Cp2,
//       Kc=512, f32 partials, M=1985 guard. (fast path)
// ---------------------------------------------------------------------------
template<bool AF32, int OM>
__global__ __launch_bounds__(256)
void gemm128(const void* __restrict__ Ap, int lda,
             const u16* __restrict__ Bp, int ldb,
             void* __restrict__ Cp, void* __restrict__ Cp2,
             int M, int Kc, int row_off, int nNt)
{
    __shared__ char As[128*128];
    __shared__ char Bs[128*128];
    const int tid  = threadIdx.x;
    const int lane = tid & 63, wave = tid >> 6;
    const int li = lane & 15, lg = lane >> 4;
    const int wr = wave >> 1, wc = wave & 1;

    const int nwg  = gridDim.x;
    const int lin  = blockIdx.x;
    int lin2 = (lin & 7) * (nwg >> 3) + (lin >> 3);
    int kh = 0;
    if (OM == 5) { kh = lin2 >= 128; lin2 -= kh*128; }
    const long bm = (long)(lin2 / nNt) * 128;
    const long bn = (long)(lin2 % nNt) * 128;
    const int kbase = (OM == 5) ? kh*512 : 0;

    const int grow = wave*32 + (lane >> 3);
    const int gcol = ((lane & 7) ^ (lane >> 3)) << 3;
    const int sr = tid >> 1, sc = (tid & 1) * 32;
    long arow_f = bm + sr; if (arow_f >= M) arow_f = M - 1;
    long arow_g[4];
    #pragma unroll
    for (int j = 0; j < 4; j++) {
        long r = bm + grow + j*8;
        arow_g[j] = (r < M) ? r : (M - 1);
    }

    f32x4 acc[4][4] = {};

    for (int k0c = 0; k0c < Kc; k0c += 64) {
        const int k0 = k0c + kbase;
        float4 a4[8];
        if (AF32) {
            const float4* ap = (const float4*)((const float*)Ap + arow_f*lda + k0 + sc);
            #pragma unroll
            for (int i = 0; i < 8; i++) a4[i] = ap[i];
        }
        __syncthreads();
        if (!AF32) {
            #pragma unroll
            for (int j = 0; j < 4; j++)
                gl_lds16((const u16*)Ap + arow_g[j]*(long)lda + k0 + gcol,
                         As + (wave*4 + j)*1024);
        }
        #pragma unroll
        for (int j = 0; j < 4; j++)
            gl_lds16(Bp + (bn + grow + j*8)*(long)ldb + k0 + gcol,
                     Bs + (wave*4 + j)*1024);
        if (AF32) {
            #pragma unroll
            for (int i = 0; i < 4; i++) {
                float4 f0 = a4[2*i], f1 = a4[2*i+1];
                bf16x8v w;
                w[0]=(__bf16)f0.x; w[1]=(__bf16)f0.y; w[2]=(__bf16)f0.z; w[3]=(__bf16)f0.w;
                w[4]=(__bf16)f1.x; w[5]=(__bf16)f1.y; w[6]=(__bf16)f1.z; w[7]=(__bf16)f1.w;
                *(bf16x8v*)(As + swz(sr, sc*2 + i*16)) = w;
            }
        }
        __syncthreads();
        #pragma unroll
        for (int es = 0; es < 2; es++) {
            bf16x8v af[4], bfv[4];
            #pragma unroll
            for (int mt = 0; mt < 4; mt++)
                af[mt] = *(const bf16x8v*)(As + swz(wr*64 + mt*16 + li, es*64 + lg*16));
            #pragma unroll
            for (int nt = 0; nt < 4; nt++)
                bfv[nt] = *(const bf16x8v*)(Bs + swz(wc*64 + nt*16 + li, es*64 + lg*16));
            #pragma unroll
            for (int mt = 0; mt < 4; mt++)
                #pragma unroll
                for (int nt = 0; nt < 4; nt++)
                    acc[mt][nt] = __builtin_amdgcn_mfma_f32_16x16x32_bf16(
                        af[mt], bfv[nt], acc[mt][nt], 0, 0, 0);
        }
    }

    #pragma unroll
    for (int mt = 0; mt < 4; mt++) {
        #pragma unroll
        for (int nt = 0; nt < 4; nt++) {
            f32x4 c = acc[mt][nt];
            const long row0 = bm + wr*64 + mt*16 + lg*4;
            const long col  = bn + wc*64 + nt*16 + li;
            if (OM == 0) {
                u16* C = (u16*)Cp;
                #pragma unroll
                for (int j = 0; j < 4; j++) {
                    long rg = row0 + j;
                    if (rg < M) C[rg*1024 + col] = f2b(c[j]);
                }
            } else if (OM == 2) {
                float* C = (float*)Cp;
                #pragma unroll
                for (int j = 0; j < 4; j++) {
                    long rg = row0 + j;
                    if (rg < M) C[(row_off + rg)*1024 + col] = c[j];
                }
            } else if (OM == 5) {
                float* C = kh ? (float*)Cp2 : (float*)Cp;
                #pragma unroll
                for (int j = 0; j < 4; j++) {
                    long rg = row0 + j;
                    if (rg < M) C[rg*1024 + col] = c[j];
                }
            } else {
                if (col < 1024) {
                    u16* Ka = (u16*)Cp;
                    #pragma unroll
                    for (int j = 0; j < 4; j++) Ka[(row0 + j)*1024 + col] = f2b(c[j]);
                } else {
                    u16* Vt = (u16*)Cp2;
                    bf16x4v w;
                    #pragma unroll
                    for (int j = 0; j < 4; j++) w[j] = (__bf16)c[j];
                    *(bf16x4v*)(Vt + (col - 1024)*32768L + row0) = w;
                }
            }
        }
    }
}

// combine: out[63+r] = Pa[r] + Pb[r], 1985x1024 f32; grid 1985 x 256 x f32x4.
__global__ __launch_bounds__(256)
void combine_wo(const float* __restrict__ Pa, const float* __restrict__ Pb,
                float* __restrict__ out)
{
    const long i = ((long)blockIdx.x*256 + threadIdx.x) * 4;   // 1985*256*4 elems exact
    f32x4 a = *(const f32x4*)(Pa + i);
    f32x4 b = *(const f32x4*)(Pb + i);
    f32x4 r = { a[0]+b[0], a[1]+b[1], a[2]+b[2], a[3]+b[3] };
    *(f32x4*)(out + 63*1024 + i) = r;
}

// ---------------------------------------------------------------------------
// Fused attention: grid (32, 16). u<31: attention. u==31: tail (last-token
// sums + head copy), r18-verified.
// ---------------------------------------------------------------------------
__global__ __launch_bounds__(256)
void attn_kernel(const u16* __restrict__ Qa, const u16* __restrict__ Ka,
                 const u16* __restrict__ Vt, u16* __restrict__ Om,
                 const float* __restrict__ x, float* __restrict__ out)
{
    const int u = blockIdx.x, h = blockIdx.y;
    const int tid = threadIdx.x;
    const int lane = tid & 63, wave = tid >> 6;
    const int li = lane & 15, lg = lane >> 4;

    if (u == 31) {
        #pragma unroll 4
        for (int it = 0; it < 16; ++it) {
            const int row = h*64 + it*4 + wave;
            const u16* p = Vt + (long)row*32768 + 31*1024 + lane*16;
            float s = 0.f;
            #pragma unroll
            for (int hf = 0; hf < 2; hf++) {
                bf16x8v v = *(const bf16x8v*)(p + hf*8);
                #pragma unroll
                for (int i = 0; i < 8; i++) s += (float)v[i];
            }
            #pragma unroll
            for (int m = 1; m < 64; m <<= 1) s += __shfl_xor(s, m);
            if (lane == 0) Om[(long)1984*1024 + row] = f2b(0.5f * s);
        }
        for (int i = h*1008 + tid; i < (h + 1)*1008; i += 256)
            ((float4*)out)[i] = ((const float4*)x)[i];
        return;
    }

    bf16x8v qf[4][2];
    #pragma unroll
    for (int qt = 0; qt < 4; qt++)
        #pragma unroll
        for (int es = 0; es < 2; es++)
            qf[qt][es] = *(const bf16x8v*)(Qa + (long)(63 + u*64 + qt*16 + li)*1024
                                              + h*64 + es*32 + lg*8);

    f32x4 acc[4][4] = {};

    for (int it = wave; it < 64; it += 4) {
        const int k = it >> 5, rsub = it & 31;
        const long kr = (long)u*1024 + k*512 + rsub*16;

        bf16x8v a0 = *(const bf16x8v*)(Ka + (kr + li)*1024 + h*64 + lg*8);
        bf16x8v a1 = *(const bf16x8v*)(Ka + (kr + li)*1024 + h*64 + 32 + lg*8);
        s16x4 va[4];
        #pragma unroll
        for (int et = 0; et < 4; et++)
            va[et] = *(const s16x4*)(Vt + (long)(h*64 + et*16 + li)*32768 + kr + lg*4);

        f32x4 s[4];
        #pragma unroll
        for (int qt = 0; qt < 4; qt++) {
            f32x4 c = {};
            c = __builtin_amdgcn_mfma_f32_16x16x32_bf16(a0, qf[qt][0], c, 0, 0, 0);
            c = __builtin_amdgcn_mfma_f32_16x16x32_bf16(a1, qf[qt][1], c, 0, 0, 0);
            s[qt] = c;
        }
        float p[4][4];
        #pragma unroll
        for (int qt = 0; qt < 4; qt++)
            #pragma unroll
            for (int j = 0; j < 4; j++)
                p[qt][j] = __builtin_amdgcn_exp2f(s[qt][j]);
        float rz[4];
        #pragma unroll
        for (int j = 0; j < 4; j++) {
            float z = p[0][j] + p[1][j] + p[2][j] + p[3][j];
            z += __shfl_xor(z, 1); z += __shfl_xor(z, 2);
            z += __shfl_xor(z, 4); z += __shfl_xor(z, 8);
            rz[j] = __builtin_amdgcn_rcpf(z);
        }
        s16x4 wf[4];
        #pragma unroll
        for (int qt = 0; qt < 4; qt++) {
            bf16x4v w;
            #pragma unroll
            for (int j = 0; j < 4; j++) w[j] = (__bf16)(p[qt][j] * rz[j]);
            wf[qt] = __builtin_bit_cast(s16x4, w);
        }
        #pragma unroll
        for (int et = 0; et < 4; et++)
            #pragma unroll
            for (int qt = 0; qt < 4; qt++)
                acc[et][qt] = __builtin_amdgcn_mfma_f32_16x16x16bf16_1k(
                    va[et], wf[qt], acc[et][qt], 0, 0, 0);
    }

    __shared__ float Osum[64*64];
    for (int w = 0; w < 4; w++) {
        if (wave == w) {
            #pragma unroll
            for (int et = 0; et < 4; et++)
                #pragma unroll
                for (int qt = 0; qt < 4; qt++)
                    #pragma unroll
                    for (int j = 0; j < 4; j++) {
                        int e = et*16 + lg*4 + j, q = qt*16 + li;
                        if (w == 0) Osum[e*64 + q]  = acc[et][qt][j];
                        else        Osum[e*64 + q] += acc[et][qt][j];
                    }
        }
        __syncthreads();
    }
    const int q = tid & 63, e0 = (tid >> 6) * 16;
    u16x8 o0, o1;
    #pragma unroll
    for (int i = 0; i < 8; i++) {
        o0[i] = f2b(0.5f * Osum[(e0 + i    )*64 + q]);
        o1[i] = f2b(0.5f * Osum[(e0 + 8 + i)*64 + q]);
    }
    u16* dst = Om + (long)(u*64 + q)*1024 + h*64 + e0;
    *(u16x8*)dst       = o0;
    *(u16x8*)(dst + 8) = o1;
}

// ---------------------------------------------------------------------------
// merged f32->bf16 converts: weights (Wq scaled) + optionally nb and x.
// ---------------------------------------------------------------------------
__global__ __launch_bounds__(256)
void convert_all(const float* __restrict__ Wq, const float* __restrict__ Wk,
                 const float* __restrict__ Wv, const float* __restrict__ Wo,
                 const float* __restrict__ nb, const float* __restrict__ x,
                 u16* __restrict__ wW, u16* __restrict__ Anb,
                 u16* __restrict__ xb, int doA)
{
    const int NW = 524288, NN = 4194304, NX = 262144;
    const int tot = doA ? (NW + NN + NX) : NW;
    const int stride = gridDim.x*256;
    for (int i = blockIdx.x*256 + threadIdx.x; i < tot; i += stride) {
        const float* s; u16* d; float sc = 1.0f;
        if (i < NW) {
            int w = i >> 17;
            long off = (long)(i & 131071) * 8;
            s = (w == 0) ? Wq : (w == 1) ? Wk : (w == 2) ? Wv : Wo;
            s += off;
            d = wW + (long)w*1048576 + off;
            if (w == 0) sc = SCALE_LOG2E;
        } else if (i < NW + NN) {
            long off = (long)(i - NW) * 8;
            s = nb + off; d = Anb + off;
        } else {
            long off = (long)(i - NW - NN) * 8;
            s = x + off; d = xb + off;
        }
        float4 f0 = ((const float4*)s)[0], f1 = ((const float4*)s)[1];
        u16x8 o = { f2b(f0.x*sc), f2b(f0.y*sc), f2b(f0.z*sc), f2b(f0.w*sc),
                    f2b(f1.x*sc), f2b(f1.y*sc), f2b(f1.z*sc), f2b(f1.w*sc) };
        *(u16x8*)d = o;
    }
}

// ---------------------------------------------------------------------------
extern "C" void kernel_launch(void* const* d_in, const int* in_sizes, int n_in,
                              void* d_out, int out_size, void* d_ws, size_t ws_size,
                              hipStream_t stream)
{
    const float* x  = (const float*)d_in[0];
    const float* nb = (const float*)d_in[1];
    const float* Wq = (const float*)d_in[2];
    const float* Wk = (const float*)d_in[3];
    const float* Wv = (const float*)d_in[4];
    const float* Wo = (const float*)d_in[5];
    float* out = (float*)d_out;
    char*  ws  = (char*)d_ws;

    // ws layout:
    //  [0,8MB)     : bf16 weights Wq(scaled),Wk,Wv,Wo (Wk:Wv contiguous = fused B)
    //  [8,12MB)    : Qa  2048x1024 bf16
    //  [12,16MB)   : Om  2048x1024 bf16 (rows 0..1984 used)
    //  [16,80MB)   : Ka  32768x1024 bf16
    //  [80,144MB)  : Vt  1024x32768 bf16
    //  [144,208MB) : Anb 32768x1024 bf16 (fast path; REUSED after gemm256 as
    //                f32 Wo partials Pa@144MB, Pb@160MB, 8.13MB each)
    //  [208,212MB) : xb  2048x1024 bf16   (fast path only)
    if (ws_size < (size_t)144*1024*1024) return;
    const bool big = ws_size >= (size_t)212*1024*1024;
    u16* wW  = (u16*)ws;
    u16* Qa  = (u16*)(ws + (size_t) 8*1024*1024);
    u16* Om  = (u16*)(ws + (size_t)12*1024*1024);
    u16* Ka  = (u16*)(ws + (size_t)16*1024*1024);
    u16* Vt  = (u16*)(ws + (size_t)80*1024*1024);
    u16* Anb = (u16*)(ws + (size_t)144*1024*1024);
    u16* xb  = (u16*)(ws + (size_t)208*1024*1024);
    float* Pa = (float*)(ws + (size_t)144*1024*1024);
    float* Pb = (float*)(ws + (size_t)160*1024*1024);
    u16* wWq = wW, *wWk = wW + 1048576, *wWo = wW + 3*1048576;

    convert_all<<<dim3(4096), dim3(256), 0, stream>>>(
        Wq, Wk, Wv, Wo, nb, x, wW, Anb, xb, big ? 1 : 0);

    if (big) {
        // merged KV (1024 blocks) + Q (32 blocks) projection dispatch
        gemm256<<<dim3(1056), dim3(512), 0, stream>>>(
            Anb, wWk, Ka, Vt, xb, wWq, Qa, 1024, 8);
        // attention + fused tail (u==31 row)
        attn_kernel<<<dim3(32, 16), dim3(256), 0, stream>>>(Qa, Ka, Vt, Om, x, out);
        // Wo projection: split-K x2, 256 blocks, f32 partials + combine
        gemm128<false, 5><<<dim3(256), dim3(256), 0, stream>>>(
            Om, 1024, wWo, 1024, Pa, Pb, 1985, 512, 0, 8);
        combine_wo<<<dim3(1985), dim3(256), 0, stream>>>(Pa, Pb, out);
    } else {
        gemm128<true, 0><<<dim3(128), dim3(256), 0, stream>>>(
            x, 1024, wWq, 1024, Qa, nullptr, 2048, 1024, 0, 8);
        gemm128<true, 3><<<dim3(4096), dim3(256), 0, stream>>>(
            nb, 1024, wWk, 1024, Ka, Vt, 32768, 1024, 0, 16);
        attn_kernel<<<dim3(32, 16), dim3(256), 0, stream>>>(Qa, Ka, Vt, Om, x, out);
        gemm128<false, 2><<<dim3(128), dim3(256), 0, stream>>>(
            Om, 1024, wWo, 1024, out, nullptr, 1985, 1024, 63, 8);
    }
}